// Round 9
// baseline (407.262 us; speedup 1.0000x reference)
//
#include <hip/hip_runtime.h>

// ---------------------------------------------------------------------------
// STTConformerBlock: B=4 T=2048 D=512 H=8 DH=64 INNER=2048 K=31, f32 I/O.
// All GEMMs pipelined (3-stage LDS, counted vmcnt, raw s_barrier, XCD swizzle):
//   gemm8  = 512-thr 256x128 tile (wide-N: ff1a/ff2a/qkv/pw1)
//   gemm4p = 256-thr 128x64 tile  (narrow-N: ff1b/ff2b/wo/pw2)
// Flash attention: swapped-QK^T 32x32 MFMA, LDS K/V dbuf, in-register softmax,
// row-sum via ones-row MFMA, exp2 domain, defer-max.
// ---------------------------------------------------------------------------

typedef float  f32x4   __attribute__((ext_vector_type(4)));
typedef float  f32x16  __attribute__((ext_vector_type(16)));
typedef __bf16 bf16_t;
typedef __bf16 bf16x8  __attribute__((ext_vector_type(8)));
typedef unsigned short u16;
typedef unsigned short u16x4 __attribute__((ext_vector_type(4)));
typedef unsigned short u16x8 __attribute__((ext_vector_type(8)));
typedef unsigned int   u32x4 __attribute__((ext_vector_type(4)));

#define DEVI __device__ __forceinline__

static constexpr int CB = 4, CT = 2048, CD = 512, CH = 8, CDH = 64, CINNER = 2048, CK = 31;
static constexpr int CBT = CB * CT;

DEVI u16 f2bf(float f) {
  unsigned u = __builtin_bit_cast(unsigned, f);
  u += 0x7FFFu + ((u >> 16) & 1u);
  return (u16)(u >> 16);
}
DEVI float bf2f(u16 h) { return __builtin_bit_cast(float, (unsigned)h << 16); }
DEVI float sigm(float x) { return 1.0f / (1.0f + __expf(-x)); }

DEVI unsigned cvtpk(float lo, float hi) {
  unsigned r;
  asm("v_cvt_pk_bf16_f32 %0, %1, %2" : "=v"(r) : "v"(lo), "v"(hi));
  return r;
}

DEVI void gload16(const bf16_t* g, bf16_t* l) {
  __builtin_amdgcn_global_load_lds(
      (const __attribute__((address_space(1))) unsigned int*)g,
      (__attribute__((address_space(3))) unsigned int*)l, 16, 0, 0);
}

// exact pipeline tail wait: 3 stages in flight -> 12, 2 -> 6, 1 -> 0
DEVI void pipe_wait(int t, int nt) {
  if (t + 3 <= nt)      asm volatile("s_waitcnt vmcnt(12)" ::: "memory");
  else if (t + 2 == nt) asm volatile("s_waitcnt vmcnt(6)" ::: "memory");
  else                  asm volatile("s_waitcnt vmcnt(0)" ::: "memory");
}

enum { EPI_BF = 0, EPI_SILU_BF = 1, EPI_RES = 2 };

// ---------------------------------------------------------------------------
// Pipelined wide-N GEMM: 512 thr, BM=256 BN=128 BK=64, 3-stage LDS.
// ---------------------------------------------------------------------------
template<int EPI>
__global__ __launch_bounds__(512) void gemm8(
    const bf16_t* __restrict__ A, const bf16_t* __restrict__ B,
    const float* __restrict__ bias, const float* __restrict__ res,
    void* __restrict__ Cv,
    int lda, int ldb, int ldc, int Kd, float scale)
{
  __shared__ __align__(16) bf16_t As[3][256 * 64];   // 96 KB
  __shared__ __align__(16) bf16_t Bs[3][128 * 64];   // 48 KB

  const int gx = gridDim.x;
  const int nwg = gx * gridDim.y;
  int wg = blockIdx.y * gx + blockIdx.x;
  wg = (wg & 7) * (nwg >> 3) + (wg >> 3);
  const int m0 = (wg / gx) * 256, n0 = (wg % gx) * 128;

  const int tid = threadIdx.x;
  const int wid = tid >> 6, lane = tid & 63;
  const int lrow = lane & 15, lk = lane >> 4;
  const int wm = (wid >> 1) * 64, wn = (wid & 1) * 64;   // 4x2 wave grid
  const int r = tid >> 3;
  const int cs = (((tid & 7) ^ (r & 7)) << 3);
  const int fsw = lrow & 7;

  auto stage = [&](int kt, int s) {
    const bf16_t* ga = A + (long)(m0 + r) * lda + (kt * 64 + cs);
    const bf16_t* gb = B + (long)(n0 + r) * ldb + (kt * 64 + cs);
    bf16_t* as = &As[s][0];
    bf16_t* bs = &Bs[s][0];
#pragma unroll
    for (int it = 0; it < 4; ++it)
      gload16(ga + (long)it * 64 * lda, as + tid * 8 + it * 4096);
#pragma unroll
    for (int it = 0; it < 2; ++it)
      gload16(gb + (long)it * 64 * ldb, bs + tid * 8 + it * 4096);
  };

  f32x4 acc[4][4] = {};
  const int nt = Kd / 64;

  stage(0, 0);
  stage(1, 1);
  stage(2, 2);

  int s = 0;
  for (int t = 0; t < nt; ++t) {
    pipe_wait(t, nt);
    asm volatile("s_barrier" ::: "memory");

    bf16x8 av[2][4], bv[2][4];
    const bf16_t* as = &As[s][0];
    const bf16_t* bs = &Bs[s][0];
#pragma unroll
    for (int kk = 0; kk < 2; ++kk) {
#pragma unroll
      for (int i = 0; i < 4; ++i)
        av[kk][i] = *(const bf16x8*)&as[(wm + i * 16 + lrow) * 64 + ((((kk << 2) + lk) ^ fsw) << 3)];
#pragma unroll
      for (int j = 0; j < 4; ++j)
        bv[kk][j] = *(const bf16x8*)&bs[(wn + j * 16 + lrow) * 64 + ((((kk << 2) + lk) ^ fsw) << 3)];
    }
    __builtin_amdgcn_s_setprio(1);
#pragma unroll
    for (int kk = 0; kk < 2; ++kk)
#pragma unroll
      for (int i = 0; i < 4; ++i)
#pragma unroll
        for (int j = 0; j < 4; ++j)
          acc[i][j] = __builtin_amdgcn_mfma_f32_16x16x32_bf16(av[kk][i], bv[kk][j], acc[i][j], 0, 0, 0);
    __builtin_amdgcn_s_setprio(0);

    asm volatile("s_barrier" ::: "memory");
    if (t + 3 < nt) stage(t + 3, s);
    s = (s == 2) ? 0 : s + 1;
  }

#pragma unroll
  for (int j = 0; j < 4; ++j) {
    int col = n0 + wn + j * 16 + lrow;
    float bb = bias ? bias[col] : 0.0f;
#pragma unroll
    for (int i = 0; i < 4; ++i) {
#pragma unroll
      for (int rr = 0; rr < 4; ++rr) {
        int row = m0 + wm + i * 16 + lk * 4 + rr;
        long idx = (long)row * ldc + col;
        float v = (acc[i][j][rr] + bb) * scale;
        if constexpr (EPI == EPI_SILU_BF) v *= sigm(v);
        if constexpr (EPI == EPI_RES) {
          ((float*)Cv)[idx] = res[idx] + v;
        } else {
          ((bf16_t*)Cv)[idx] = (bf16_t)v;
        }
      }
    }
  }
}

// ---------------------------------------------------------------------------
// Pipelined narrow-N GEMM: 256 thr, BM=128 BN=64 BK=64, 3-stage LDS (72 KB,
// 2 blocks/CU). Same counted-vmcnt schedule as gemm8.
// ---------------------------------------------------------------------------
template<int EPI>
__global__ __launch_bounds__(256) void gemm4p(
    const bf16_t* __restrict__ A, const bf16_t* __restrict__ B,
    const float* __restrict__ bias, const float* __restrict__ res,
    void* __restrict__ Cv,
    int lda, int ldb, int ldc, int Kd, float scale)
{
  __shared__ __align__(16) bf16_t As[3][128 * 64];   // 48 KB
  __shared__ __align__(16) bf16_t Bs[3][64 * 64];    // 24 KB

  const int gx = gridDim.x;
  const int nwg = gx * gridDim.y;
  int wg = blockIdx.y * gx + blockIdx.x;
  wg = (wg & 7) * (nwg >> 3) + (wg >> 3);
  const int m0 = (wg / gx) * 128, n0 = (wg % gx) * 64;

  const int tid = threadIdx.x;
  const int wid = tid >> 6, lane = tid & 63;
  const int lrow = lane & 15, lk = lane >> 4;
  const int wm = (wid >> 1) * 64, wn = (wid & 1) * 32;   // 2x2 wave grid
  const int r = tid >> 3;
  const int cs = (((tid & 7) ^ (r & 7)) << 3);
  const int fsw = lrow & 7;

  auto stage = [&](int kt, int s) {
    const bf16_t* ga = A + (long)(m0 + r) * lda + (kt * 64 + cs);
    const bf16_t* gb = B + (long)(n0 + r) * ldb + (kt * 64 + cs);
#pragma unroll
    for (int it = 0; it < 4; ++it)
      gload16(ga + (long)it * 32 * lda, &As[s][tid * 8 + it * 2048]);
#pragma unroll
    for (int it = 0; it < 2; ++it)
      gload16(gb + (long)it * 32 * ldb, &Bs[s][tid * 8 + it * 2048]);
  };

  f32x4 acc[4][2] = {};
  const int nt = Kd / 64;

  stage(0, 0);
  stage(1, 1);
  stage(2, 2);

  int s = 0;
  for (int t = 0; t < nt; ++t) {
    pipe_wait(t, nt);
    asm volatile("s_barrier" ::: "memory");

    bf16x8 av[2][4], bv[2][2];
    const bf16_t* as = &As[s][0];
    const bf16_t* bs = &Bs[s][0];
#pragma unroll
    for (int kk = 0; kk < 2; ++kk) {
#pragma unroll
      for (int i = 0; i < 4; ++i)
        av[kk][i] = *(const bf16x8*)&as[(wm + i * 16 + lrow) * 64 + ((((kk << 2) + lk) ^ fsw) << 3)];
#pragma unroll
      for (int j = 0; j < 2; ++j)
        bv[kk][j] = *(const bf16x8*)&bs[(wn + j * 16 + lrow) * 64 + ((((kk << 2) + lk) ^ fsw) << 3)];
    }
    __builtin_amdgcn_s_setprio(1);
#pragma unroll
    for (int kk = 0; kk < 2; ++kk)
#pragma unroll
      for (int i = 0; i < 4; ++i)
#pragma unroll
        for (int j = 0; j < 2; ++j)
          acc[i][j] = __builtin_amdgcn_mfma_f32_16x16x32_bf16(av[kk][i], bv[kk][j], acc[i][j], 0, 0, 0);
    __builtin_amdgcn_s_setprio(0);

    asm volatile("s_barrier" ::: "memory");
    if (t + 3 < nt) stage(t + 3, s);
    s = (s == 2) ? 0 : s + 1;
  }

#pragma unroll
  for (int j = 0; j < 2; ++j) {
    int col = n0 + wn + j * 16 + lrow;
    float bb = bias ? bias[col] : 0.0f;
#pragma unroll
    for (int i = 0; i < 4; ++i) {
#pragma unroll
      for (int rr = 0; rr < 4; ++rr) {
        int row = m0 + wm + i * 16 + lk * 4 + rr;
        long idx = (long)row * ldc + col;
        float v = (acc[i][j][rr] + bb) * scale;
        if constexpr (EPI == EPI_SILU_BF) v *= sigm(v);
        if constexpr (EPI == EPI_RES) {
          ((float*)Cv)[idx] = res[idx] + v;
        } else {
          ((bf16_t*)Cv)[idx] = (bf16_t)v;
        }
      }
    }
  }
}

// ---------------------------------------------------------------------------
// Flash attention (full KV). Block = 128 q-rows of one (b,h), 4 waves x
// 32 q-rows. K/V LDS double-buffered (static offsets). Softmax in-register:
// tree max + permlane32_swap; row-sum via ones-row MFMA; exp2; defer-max.
// ---------------------------------------------------------------------------
__global__ __launch_bounds__(256) void fattn_k(
    const bf16_t* __restrict__ QK,   // [B*T][1536], Q at 0, K at 512
    const bf16_t* __restrict__ VT,   // [B*H][64][2048]
    bf16_t* __restrict__ O)          // [B*T][512]
{
  __shared__ __align__(16) bf16_t S[16384];      // 32 KB

  const int tid = threadIdx.x;
  const int w = tid >> 6, lane = tid & 63;
  const int l31 = lane & 31, hi = lane >> 5;
  const int q0 = blockIdx.x * 128;
  const int bh = blockIdx.y, b = bh >> 3, h = bh & 7;

  const int r8 = tid >> 3;
  const int csw = ((tid & 7) ^ (r8 & 7)) << 3;
  const int fswl = l31 & 7;

  const bf16_t* Qg = QK + ((long)b * CT + q0) * 1536 + h * 64;
  const bf16_t* Kg = QK + (long)b * CT * 1536 + 512 + h * 64;
  const bf16_t* Vg = VT + (long)bh * 64 * 2048;

#pragma unroll
  for (int it = 0; it < 4; ++it)
    gload16(Qg + (long)(r8 + it * 32) * 1536 + csw, &S[8192 + tid * 8 + it * 2048]);
#pragma unroll
  for (int it = 0; it < 2; ++it)
    gload16(Kg + (long)(r8 + it * 32) * 1536 + csw, &S[tid * 8 + it * 2048]);
#pragma unroll
  for (int it = 0; it < 2; ++it)
    gload16(Vg + (long)(r8 + it * 32) * 2048 + csw, &S[4096 + tid * 8 + it * 2048]);
  __syncthreads();

  bf16x8 qb[4];
#pragma unroll
  for (int m = 0; m < 4; ++m)
    qb[m] = *(const bf16x8*)&S[8192 + (w * 32 + l31) * 64 + (((m * 2 + hi) ^ fswl) << 3)];
  __syncthreads();

  const u16x8 onesu = {0x3F80, 0x3F80, 0x3F80, 0x3F80, 0x3F80, 0x3F80, 0x3F80, 0x3F80};
  const bf16x8 onesf = __builtin_bit_cast(bf16x8, onesu);

  f32x16 o0 = {}, o1 = {}, lacc = {};
  float mrun = -3.0e38f;

#define FA_BODY(CURK, CURV, NXTK, NXTV, KV0, STG)                               \
  {                                                                             \
    if (STG) {                                                                  \
      const int nxt = (KV0) + 64;                                               \
      _Pragma("unroll")                                                         \
      for (int it = 0; it < 2; ++it)                                            \
        gload16(Kg + (long)(nxt + r8 + it * 32) * 1536 + csw,                   \
                &S[(NXTK) + tid * 8 + it * 2048]);                              \
      _Pragma("unroll")                                                         \
      for (int it = 0; it < 2; ++it)                                            \
        gload16(Vg + (long)(r8 + it * 32) * 2048 + nxt + csw,                   \
                &S[(NXTV) + tid * 8 + it * 2048]);                              \
    }                                                                           \
    bf16x8 ka[2][4];                                                            \
    _Pragma("unroll")                                                           \
    for (int j = 0; j < 2; ++j)                                                 \
      _Pragma("unroll")                                                         \
      for (int m = 0; m < 4; ++m)                                               \
        ka[j][m] = *(const bf16x8*)&S[(CURK) + (j * 32 + l31) * 64 +            \
                                      (((m * 2 + hi) ^ fswl) << 3)];            \
    f32x16 s0 = {}, s1 = {};                                                    \
    __builtin_amdgcn_s_setprio(1);                                              \
    _Pragma("unroll")                                                           \
    for (int m = 0; m < 4; ++m) {                                               \
      s0 = __builtin_amdgcn_mfma_f32_32x32x16_bf16(ka[0][m], qb[m], s0, 0, 0, 0); \
      s1 = __builtin_amdgcn_mfma_f32_32x32x16_bf16(ka[1][m], qb[m], s1, 0, 0, 0); \
    }                                                                           \
    __builtin_amdgcn_s_setprio(0);                                              \
    float tm[16];                                                               \
    _Pragma("unroll")                                                           \
    for (int rr = 0; rr < 16; ++rr) tm[rr] = fmaxf(s0[rr], s1[rr]);             \
    _Pragma("unroll")                                                           \
    for (int stp = 8; stp; stp >>= 1)                                           \
      _Pragma("unroll")                                                         \
      for (int rr = 0; rr < stp; ++rr) tm[rr] = fmaxf(tm[rr], tm[rr + stp]);    \
    float pm = tm[0];                                                           \
    { float pa = pm, pb = pm;                                                   \
      asm("v_permlane32_swap_b32 %0, %1" : "+v"(pa), "+v"(pb));                 \
      pm = fmaxf(pa, pb); }                                                     \
    if (!__all(pm <= mrun + 8.0f)) {                                            \
      float mn = fmaxf(mrun, pm);                                               \
      float al = exp2f(mrun - mn);                                              \
      mrun = mn;                                                                \
      lacc[0] *= al;                                                            \
      _Pragma("unroll")                                                         \
      for (int rr = 0; rr < 16; ++rr) { o0[rr] *= al; o1[rr] *= al; }           \
    }                                                                           \
    _Pragma("unroll")                                                           \
    for (int rr = 0; rr < 16; ++rr) s0[rr] = exp2f(s0[rr] - mrun);              \
    _Pragma("unroll")                                                           \
    for (int rr = 0; rr < 16; ++rr) s1[rr] = exp2f(s1[rr] - mrun);              \
    bf16x8 pw[4];                                                               \
    _Pragma("unroll")                                                           \
    for (int jk = 0; jk < 4; ++jk) {                                            \
      float e0, e1, e2, e3, e4, e5, e6, e7;                                     \
      if (jk == 0) { e0=s0[0];e1=s0[1];e2=s0[2];e3=s0[3];e4=s0[4];e5=s0[5];e6=s0[6];e7=s0[7]; }        \
      else if (jk == 1) { e0=s0[8];e1=s0[9];e2=s0[10];e3=s0[11];e4=s0[12];e5=s0[13];e6=s0[14];e7=s0[15]; } \
      else if (jk == 2) { e0=s1[0];e1=s1[1];e2=s1[2];e3=s1[3];e4=s1[4];e5=s1[5];e6=s1[6];e7=s1[7]; }   \
      else { e0=s1[8];e1=s1[9];e2=s1[10];e3=s1[11];e4=s1[12];e5=s1[13];e6=s1[14];e7=s1[15]; }          \
      unsigned a0 = cvtpk(e0, e1), a1 = cvtpk(e2, e3);                          \
      unsigned b0 = cvtpk(e4, e5), b1 = cvtpk(e6, e7);                          \
      asm("v_permlane32_swap_b32 %0, %1" : "+v"(a0), "+v"(b0));                 \
      asm("v_permlane32_swap_b32 %0, %1" : "+v"(a1), "+v"(b1));                 \
      u32x4 t; t[0] = a0; t[1] = a1; t[2] = b0; t[3] = b1;                      \
      pw[jk] = __builtin_bit_cast(bf16x8, t);                                   \
    }                                                                           \
    bf16x8 va[2][4];                                                            \
    _Pragma("unroll")                                                           \
    for (int n = 0; n < 2; ++n)                                                 \
      _Pragma("unroll")                                                         \
      for (int jk = 0; jk < 4; ++jk)                                            \
        va[n][jk] = *(const bf16x8*)&S[(CURV) + (n * 32 + l31) * 64 +           \
                                       (((jk * 2 + hi) ^ fswl) << 3)];          \
    __builtin_amdgcn_s_setprio(1);                                              \
    _Pragma("unroll")                                                           \
    for (int jk = 0; jk < 4; ++jk) {                                            \
      o0 = __builtin_amdgcn_mfma_f32_32x32x16_bf16(va[0][jk], pw[jk], o0, 0, 0, 0); \
      o1 = __builtin_amdgcn_mfma_f32_32x32x16_bf16(va[1][jk], pw[jk], o1, 0, 0, 0); \
      lacc = __builtin_amdgcn_mfma_f32_32x32x16_bf16(onesf, pw[jk], lacc, 0, 0, 0); \
    }                                                                           \
    __builtin_amdgcn_s_setprio(0);                                              \
    __syncthreads();                                                            \
  }

  for (int kv0 = 0; kv0 < CT; kv0 += 128) {
    FA_BODY(0, 4096, 8192, 12288, kv0, 1)
    FA_BODY(8192, 12288, 0, 4096, kv0 + 64, (kv0 + 128 < CT))
  }
#undef FA_BODY

  float rl = 1.0f / lacc[0];
  bf16_t* Op = O + ((long)b * CT + q0 + w * 32 + l31) * CD + h * 64;
#pragma unroll
  for (int n = 0; n < 2; ++n) {
#pragma unroll
    for (int m = 0; m < 4; ++m) {
      u16x4 pk4;
#pragma unroll
      for (int e = 0; e < 4; ++e)
        pk4[e] = f2bf((n ? o1[m * 4 + e] : o0[m * 4 + e]) * rl);
      *(u16x4*)(Op + n * 32 + m * 8 + hi * 4) = pk4;
    }
  }
}

// ---------------------------------------------------------------------------
// Weight convert+transpose: w[K][N] f32 -> o[N][K] bf16. 64x64 tiles.
// ---------------------------------------------------------------------------
__global__ __launch_bounds__(256) void wtrans_k(
    const float* __restrict__ w, u16* __restrict__ o, int Kd, int N)
{
  __shared__ u16 lt[64][72];
  const int k0 = blockIdx.y * 64, n0 = blockIdx.x * 64;
  const int tid = threadIdx.x;
#pragma unroll
  for (int it = 0; it < 4; ++it) {
    int kk = (tid >> 4) + it * 16, nn = (tid & 15) * 4;
    float4 f = *(const float4*)(w + (long)(k0 + kk) * N + n0 + nn);
    lt[kk][nn + 0] = f2bf(f.x); lt[kk][nn + 1] = f2bf(f.y);
    lt[kk][nn + 2] = f2bf(f.z); lt[kk][nn + 3] = f2bf(f.w);
  }
  __syncthreads();
#pragma unroll
  for (int it = 0; it < 2; ++it) {
    int nn = (tid >> 3) + it * 32, kk = (tid & 7) * 8;
    u16x8 pk;
#pragma unroll
    for (int e = 0; e < 8; ++e) pk[e] = lt[kk + e][nn];
    *(u16x8*)(o + (long)(n0 + nn) * Kd + k0 + kk) = pk;
  }
}

// V columns of bufQKV -> VT[bh][d][t]
__global__ __launch_bounds__(256) void vtrans_k(
    const u16* __restrict__ v, u16* __restrict__ vt)
{
  __shared__ u16 lt[64][72];
  const int bh = blockIdx.y, b = bh >> 3, h = bh & 7;
  const int t0 = blockIdx.x * 64;
  const int tid = threadIdx.x;
#pragma unroll
  for (int it = 0; it < 2; ++it) {
    int tt = (tid >> 3) + it * 32, dd = (tid & 7) * 8;
    u16x8 vv = *(const u16x8*)(v + ((long)b * CT + t0 + tt) * 1536 + 1024 + h * 64 + dd);
#pragma unroll
    for (int e = 0; e < 8; ++e) lt[tt][dd + e] = vv[e];
  }
  __syncthreads();
#pragma unroll
  for (int it = 0; it < 2; ++it) {
    int dd = (tid >> 3) + it * 32, tt = (tid & 7) * 8;
    u16x8 pk;
#pragma unroll
    for (int e = 0; e < 8; ++e) pk[e] = lt[tt + e][dd];
    *(u16x8*)(vt + ((long)bh * 64 + dd) * CT + t0 + tt) = pk;
  }
}

// dw_w[512][31] f32 -> wT[31][512] f32
__global__ void dwt_k(const float* __restrict__ w, float* __restrict__ o)
{
  int i = blockIdx.x * 256 + threadIdx.x;
  if (i < 512 * 31) { int c = i / 31, k = i % 31; o[k * 512 + c] = w[i]; }
}

// ---------------------------------------------------------------------------
// LayerNorm over D=512, one block per row.
// ---------------------------------------------------------------------------
template<int OBF>
__global__ __launch_bounds__(256) void ln_k(
    const float* __restrict__ in, const float* __restrict__ g,
    const float* __restrict__ b, void* __restrict__ out)
{
  __shared__ float rs[4], rq[4];
  const long row = blockIdx.x;
  const int tid = threadIdx.x;
  float2 v = ((const float2*)(in + row * CD))[tid];
  float s = v.x + v.y, q = v.x * v.x + v.y * v.y;
#pragma unroll
  for (int o = 32; o; o >>= 1) { s += __shfl_xor(s, o); q += __shfl_xor(q, o); }
  if ((tid & 63) == 0) { rs[tid >> 6] = s; rq[tid >> 6] = q; }
  __syncthreads();
  s = rs[0] + rs[1] + rs[2] + rs[3];
  q = rq[0] + rq[1] + rq[2] + rq[3];
  float mean = s * (1.0f / CD);
  float var = q * (1.0f / CD) - mean * mean;
  float rstd = rsqrtf(var + 1e-5f);
  float2 gg = ((const float2*)g)[tid];
  float2 bb = ((const float2*)b)[tid];
  float ox = (v.x - mean) * rstd * gg.x + bb.x;
  float oy = (v.y - mean) * rstd * gg.y + bb.y;
  if (OBF) {
    unsigned pk = ((unsigned)f2bf(oy) << 16) | f2bf(ox);
    ((unsigned*)out)[row * 256 + tid] = pk;
  } else {
    ((float2*)out)[row * 256 + tid] = make_float2(ox, oy);
  }
}

__global__ void rope_table_k(float* __restrict__ cosT, float* __restrict__ sinT)
{
  int tid = blockIdx.x * 256 + threadIdx.x;     // T*32
  int t = tid >> 5, i = tid & 31;
  float freq = __expf(-(float)i * (9.210340371976184f / 32.0f));
  float ang = (float)t * freq;
  cosT[tid] = cosf(ang);
  sinT[tid] = sinf(ang);
}

// In-place RoPE on fused QKV (Q cols 0..511 scaled by 0.125*log2e, K 512..1023).
__global__ __launch_bounds__(256) void rope_k(
    unsigned* __restrict__ qkv,
    const float* __restrict__ cosT, const float* __restrict__ sinT)
{
  const float SC = 0.125f * 1.44269504089f;
  long p = (long)blockIdx.x * 256 + threadIdx.x;
  int pr = (int)(p & 255);
  long row = p >> 8;
  int t = (int)(row & (CT - 1));
  int h = pr >> 5, i = pr & 31;
  float c = cosT[t * 32 + i], s = sinT[t * 32 + i];
  unsigned* base = qkv + row * 768 + h * 32 + i;
  unsigned v = base[0];
  float xe = bf2f((u16)v), xo = bf2f((u16)(v >> 16));
  base[0] = ((unsigned)f2bf((xe * s + xo * c) * SC) << 16) | f2bf((xe * c - xo * s) * SC);
  v = base[256];
  xe = bf2f((u16)v); xo = bf2f((u16)(v >> 16));
  base[256] = ((unsigned)f2bf(xe * s + xo * c) << 16) | f2bf(xe * c - xo * s);
}

// GLU
__global__ __launch_bounds__(256) void glu_k(
    const u16* __restrict__ t, u16* __restrict__ out)
{
  long idx = (long)blockIdx.x * 256 + threadIdx.x;
  long row = idx >> 7;
  int c4 = (int)(idx & 127) * 4;
  u16x4 a = *(const u16x4*)(t + row * 1024 + c4);
  u16x4 b = *(const u16x4*)(t + row * 1024 + 512 + c4);
  u16x4 o;
#pragma unroll
  for (int e = 0; e < 4; ++e) o[e] = f2bf(bf2f(a[e]) * sigm(bf2f(b[e])));
  *(u16x4*)(out + row * CD + c4) = o;
}

// Depthwise conv1d: bf16 in, bf16 out. 8 t-outputs x 4 channels/thread.
__global__ __launch_bounds__(256) void dwconv_k(
    const u16* __restrict__ in, const float* __restrict__ wT,
    const float* __restrict__ wb, u16* __restrict__ out)
{
  long idx = (long)blockIdx.x * 256 + threadIdx.x;
  int c4 = (int)(idx & 127) * 4;
  int t0 = (int)((idx >> 7) & 255) * 8;
  int b = (int)(idx >> 15);
  const u16* base = in + (long)b * CT * CD;
  float4 bias = *(const float4*)(wb + c4);
  float4 acc[8];
#pragma unroll
  for (int t = 0; t < 8; ++t) acc[t] = bias;
#pragma unroll
  for (int j = 0; j < 38; ++j) {
    int tr = t0 + j - 15;
    float4 row = make_float4(0.f, 0.f, 0.f, 0.f);
    if (tr >= 0 && tr < CT) {
      u16x4 rv = *(const u16x4*)(base + (long)tr * CD + c4);
      row = make_float4(bf2f(rv[0]), bf2f(rv[1]), bf2f(rv[2]), bf2f(rv[3]));
    }
#pragma unroll
    for (int t = 0; t < 8; ++t) {
      int k = j - t;
      if (k >= 0 && k < CK) {
        float4 w4 = *(const float4*)(wT + k * CD + c4);
        acc[t].x += row.x * w4.x; acc[t].y += row.y * w4.y;
        acc[t].z += row.z * w4.z; acc[t].w += row.w * w4.w;
      }
    }
  }
#pragma unroll
  for (int t = 0; t < 8; ++t) {
    u16x4 pk;
    pk[0] = f2bf(acc[t].x); pk[1] = f2bf(acc[t].y);
    pk[2] = f2bf(acc[t].z); pk[3] = f2bf(acc[t].w);
    *(u16x4*)(out + ((long)b * CT + t0 + t) * CD + c4) = pk;
  }
}

__global__ __launch_bounds__(256) void bn_part_k(
    const u16* __restrict__ in, float* __restrict__ psum, float* __restrict__ psq)
{
  const int blk = blockIdx.x;        // 256
  const int tid = threadIdx.x;
  const int c0 = tid, c1 = tid + 256;
  const int rows = CBT / 256;
  const u16* base = in + (long)blk * rows * CD;
  float s0 = 0, q0 = 0, s1 = 0, q1 = 0;
  for (int r = 0; r < rows; ++r) {
    float v0 = bf2f(base[(long)r * CD + c0]); s0 += v0; q0 += v0 * v0;
    float v1 = bf2f(base[(long)r * CD + c1]); s1 += v1; q1 += v1 * v1;
  }
  psum[blk * CD + c0] = s0; psq[blk * CD + c0] = q0;
  psum[blk * CD + c1] = s1; psq[blk * CD + c1] = q1;
}

__global__ __launch_bounds__(256) void bn_fin_k(
    const float* __restrict__ psum, const float* __restrict__ psq,
    float* __restrict__ stat)
{
  int c = blockIdx.x * 256 + threadIdx.x;
  float s = 0, q = 0;
  for (int i = 0; i < 256; ++i) { s += psum[i * CD + c]; q += psq[i * CD + c]; }
  float mean = s * (1.0f / CBT);
  float var = q * (1.0f / CBT) - mean * mean;
  stat[c] = mean;
  stat[CD + c] = rsqrtf(var + 1e-5f);
}

__global__ __launch_bounds__(256) void bn_app_k(
    const u16* __restrict__ h, const float* __restrict__ stat,
    const float* __restrict__ g, const float* __restrict__ b,
    u16* __restrict__ out)
{
  long idx = (long)blockIdx.x * 256 + threadIdx.x;
  int c = (int)(idx & 511);
  float v = (bf2f(h[idx]) - stat[c]) * stat[CD + c] * g[c] + b[c];
  v = v * sigm(v);
  out[idx] = f2bf(v);
}

// ---------------------------------------------------------------------------
// Host launcher
// ---------------------------------------------------------------------------
extern "C" void kernel_launch(void* const* d_in, const int* in_sizes, int n_in,
                              void* d_out, int out_size, void* d_ws, size_t ws_size,
                              hipStream_t stream)
{
  const float* x        = (const float*)d_in[0];
  const float* ff1_lng  = (const float*)d_in[1];
  const float* ff1_lnb  = (const float*)d_in[2];
  const float* ff1_w1   = (const float*)d_in[3];
  const float* ff1_b1   = (const float*)d_in[4];
  const float* ff1_w2   = (const float*)d_in[5];
  const float* ff1_b2   = (const float*)d_in[6];
  const float* attn_lng = (const float*)d_in[7];
  const float* attn_lnb = (const float*)d_in[8];
  const float* wq       = (const float*)d_in[9];
  const float* wk       = (const float*)d_in[10];
  const float* wv       = (const float*)d_in[11];
  const float* wo       = (const float*)d_in[12];
  const float* conv_lng = (const float*)d_in[13];
  const float* conv_lnb = (const float*)d_in[14];
  const float* pw1_w    = (const float*)d_in[15];
  const float* pw1_b    = (const float*)d_in[16];
  const float* dw_w     = (const float*)d_in[17];
  const float* dw_b     = (const float*)d_in[18];
  const float* bn_g     = (const float*)d_in[19];
  const float* bn_b     = (const float*)d_in[20];
  const float* pw2_w    = (const float*)d_in[21];
  const float* pw2_b    = (const float*)d_in[22];
  const float* ff2_lng  = (const float*)d_in[23];
  const float* ff2_lnb  = (const float*)d_in[24];
  const float* ff2_w1   = (const float*)d_in[25];
  const float* ff2_b1   = (const float*)d_in[26];
  const float* ff2_w2   = (const float*)d_in[27];
  const float* ff2_b2   = (const float*)d_in[28];
  const float* out_lng  = (const float*)d_in[29];
  const float* out_lnb  = (const float*)d_in[30];
  float* out = (float*)d_out;

  char* p = (char*)d_ws;
  auto alloc = [&](size_t bytes) { char* r = p; p += (bytes + 255) & ~(size_t)255; return r; };
  float*  bufX   = (float*)alloc((size_t)CBT * CD * 4);
  bf16_t* bufH   = (bf16_t*)alloc((size_t)CBT * CD * 2);
  bf16_t* bufQKV = (bf16_t*)alloc((size_t)CBT * 1536 * 2);
  bf16_t* bufO   = (bf16_t*)alloc((size_t)CBT * CD * 2);
  bf16_t* bufVT  = (bf16_t*)alloc((size_t)CBT * CD * 2);
  bf16_t* bufP   = (bf16_t*)alloc((size_t)CBT * CINNER * 2);
  bf16_t* w_ff1a = (bf16_t*)alloc((size_t)CD * CINNER * 2);
  bf16_t* w_ff1b = (bf16_t*)alloc((size_t)CD * CINNER * 2);
  bf16_t* w_qkv  = (bf16_t*)alloc((size_t)CD * 1536 * 2);
  bf16_t* w_o    = (bf16_t*)alloc((size_t)CD * CD * 2);
  bf16_t* w_pw1  = (bf16_t*)alloc((size_t)CD * 2 * CD * 2);
  bf16_t* w_pw2  = (bf16_t*)alloc((size_t)CD * CD * 2);
  bf16_t* w_ff2a = (bf16_t*)alloc((size_t)CD * CINNER * 2);
  bf16_t* w_ff2b = (bf16_t*)alloc((size_t)CD * CINNER * 2);
  float* dwT  = (float*)alloc((size_t)CK * CD * 4);
  float* cosT = (float*)alloc((size_t)CT * 32 * 4);
  float* sinT = (float*)alloc((size_t)CT * 32 * 4);
  float* psum = (float*)alloc((size_t)256 * CD * 4);
  float* psq  = (float*)alloc((size_t)256 * CD * 4);
  float* stat = (float*)alloc((size_t)2 * CD * 4);

  const dim3 blk(256);
  const dim3 blk8(512);

  wtrans_k<<<dim3(CINNER / 64, CD / 64), blk, 0, stream>>>(ff1_w1, (u16*)w_ff1a, CD, CINNER);
  wtrans_k<<<dim3(CD / 64, CINNER / 64), blk, 0, stream>>>(ff1_w2, (u16*)w_ff1b, CINNER, CD);
  wtrans_k<<<dim3(CD / 64, CD / 64), blk, 0, stream>>>(wq, (u16*)w_qkv, CD, CD);
  wtrans_k<<<dim3(CD / 64, CD / 64), blk, 0, stream>>>(wk, (u16*)(w_qkv + (size_t)512 * CD), CD, CD);
  wtrans_k<<<dim3(CD / 64, CD / 64), blk, 0, stream>>>(wv, (u16*)(w_qkv + (size_t)1024 * CD), CD, CD);
  wtrans_k<<<dim3(CD / 64, CD / 64), blk, 0, stream>>>(wo, (u16*)w_o, CD, CD);
  wtrans_k<<<dim3(2 * CD / 64, CD / 64), blk, 0, stream>>>(pw1_w, (u16*)w_pw1, CD, 2 * CD);
  wtrans_k<<<dim3(CD / 64, CD / 64), blk, 0, stream>>>(pw2_w, (u16*)w_pw2, CD, CD);
  wtrans_k<<<dim3(CINNER / 64, CD / 64), blk, 0, stream>>>(ff2_w1, (u16*)w_ff2a, CD, CINNER);
  wtrans_k<<<dim3(CD / 64, CINNER / 64), blk, 0, stream>>>(ff2_w2, (u16*)w_ff2b, CINNER, CD);
  dwt_k<<<dim3(62), blk, 0, stream>>>(dw_w, dwT);
  rope_table_k<<<dim3(CT * 32 / 256), blk, 0, stream>>>(cosT, sinT);

  // ---- FF1 ----
  ln_k<1><<<dim3(CBT), blk, 0, stream>>>(x, ff1_lng, ff1_lnb, bufH);
  gemm8<EPI_SILU_BF><<<dim3(16, 32), blk8, 0, stream>>>(
      bufH, w_ff1a, ff1_b1, nullptr, bufP, CD, CD, CINNER, CD, 1.0f);
  gemm4p<EPI_RES><<<dim3(8, 64), blk, 0, stream>>>(
      bufP, w_ff1b, ff1_b2, x, bufX, CINNER, CINNER, CD, CINNER, 0.5f);

  // ---- Attention ----
  ln_k<1><<<dim3(CBT), blk, 0, stream>>>(bufX, attn_lng, attn_lnb, bufH);
  gemm8<EPI_BF><<<dim3(12, 32), blk8, 0, stream>>>(
      bufH, w_qkv, nullptr, nullptr, bufQKV, CD, CD, 1536, CD, 1.0f);
  rope_k<<<dim3(CB * CT), blk, 0, stream>>>((unsigned*)bufQKV, cosT, sinT);
  vtrans_k<<<dim3(CT / 64, CB * CH), blk, 0, stream>>>((const u16*)bufQKV, (u16*)bufVT);
  fattn_k<<<dim3(CT / 128, CB * CH), blk, 0, stream>>>(bufQKV, bufVT, bufO);
  gemm4p<EPI_RES><<<dim3(8, 64), blk, 0, stream>>>(
      bufO, w_o, nullptr, bufX, bufX, CD, CD, CD, CD, 1.0f);

  // ---- Conv module ----
  ln_k<1><<<dim3(CBT), blk, 0, stream>>>(bufX, conv_lng, conv_lnb, bufH);
  gemm8<EPI_BF><<<dim3(8, 32), blk8, 0, stream>>>(
      bufH, w_pw1, pw1_b, nullptr, bufP, CD, CD, 2 * CD, CD, 1.0f);
  glu_k<<<dim3(CBT * 128 / 256), blk, 0, stream>>>((const u16*)bufP, (u16*)bufH);
  dwconv_k<<<dim3(512), blk, 0, stream>>>((const u16*)bufH, dwT, dw_b, (u16*)bufO);
  bn_part_k<<<dim3(256), blk, 0, stream>>>((const u16*)bufO, psum, psq);
  bn_fin_k<<<dim3(2), blk, 0, stream>>>(psum, psq, stat);
  bn_app_k<<<dim3(CBT * CD / 256), blk, 0, stream>>>((const u16*)bufO, stat, bn_g, bn_b, (u16*)bufH);
  gemm4p<EPI_RES><<<dim3(8, 64), blk, 0, stream>>>(
      bufH, w_pw2, pw2_b, bufX, bufX, CD, CD, CD, CD, 1.0f);

  // ---- FF2 ----
  ln_k<1><<<dim3(CBT), blk, 0, stream>>>(bufX, ff2_lng, ff2_lnb, bufH);
  gemm8<EPI_SILU_BF><<<dim3(16, 32), blk8, 0, stream>>>(
      bufH, w_ff2a, ff2_b1, nullptr, bufP, CD, CD, CINNER, CD, 1.0f);
  gemm4p<EPI_RES><<<dim3(8, 64), blk, 0, stream>>>(
      bufP, w_ff2b, ff2_b2, bufX, bufX, CINNER, CINNER, CD, CINNER, 0.5f);

  // ---- Output LN ----
  ln_k<0><<<dim3(CBT), blk, 0, stream>>>(bufX, out_lng, out_lnb, out);

  (void)in_sizes; (void)n_in; (void)out_size; (void)ws_size;
}

// Round 10
// 405.954 us; speedup vs baseline: 1.0032x; 1.0032x over previous
//
#include <hip/hip_runtime.h>

// ---------------------------------------------------------------------------
// STTConformerBlock: B=4 T=2048 D=512 H=8 DH=64 INNER=2048 K=31, f32 I/O.
// All GEMMs pipelined (3-stage LDS, counted vmcnt, raw s_barrier, XCD swizzle):
//   gemm8  = 512-thr 256x128 tile (wide-N: ff1a/ff2a/qkv/pw1)
//   gemm4p = 256-thr 64x128 tile  (narrow-N: ff1b/ff2b/wo/pw2)
// Flash attention: swapped-QK^T 32x32 MFMA, LDS K/V dbuf, in-register softmax,
// row-sum via ones-row MFMA, exp2 domain, defer-max.
// ---------------------------------------------------------------------------

typedef float  f32x4   __attribute__((ext_vector_type(4)));
typedef float  f32x16  __attribute__((ext_vector_type(16)));
typedef __bf16 bf16_t;
typedef __bf16 bf16x8  __attribute__((ext_vector_type(8)));
typedef unsigned short u16;
typedef unsigned short u16x4 __attribute__((ext_vector_type(4)));
typedef unsigned short u16x8 __attribute__((ext_vector_type(8)));
typedef unsigned int   u32x4 __attribute__((ext_vector_type(4)));

#define DEVI __device__ __forceinline__

static constexpr int CB = 4, CT = 2048, CD = 512, CH = 8, CDH = 64, CINNER = 2048, CK = 31;
static constexpr int CBT = CB * CT;

DEVI u16 f2bf(float f) {
  unsigned u = __builtin_bit_cast(unsigned, f);
  u += 0x7FFFu + ((u >> 16) & 1u);
  return (u16)(u >> 16);
}
DEVI float bf2f(u16 h) { return __builtin_bit_cast(float, (unsigned)h << 16); }
DEVI float sigm(float x) { return 1.0f / (1.0f + __expf(-x)); }

DEVI unsigned cvtpk(float lo, float hi) {
  unsigned r;
  asm("v_cvt_pk_bf16_f32 %0, %1, %2" : "=v"(r) : "v"(lo), "v"(hi));
  return r;
}

DEVI void gload16(const bf16_t* g, bf16_t* l) {
  __builtin_amdgcn_global_load_lds(
      (const __attribute__((address_space(1))) unsigned int*)g,
      (__attribute__((address_space(3))) unsigned int*)l, 16, 0, 0);
}

// exact pipeline tail wait (6 loads/stage): 3 stages in flight -> 12, 2 -> 6, 1 -> 0
DEVI void pipe_wait(int t, int nt) {
  if (t + 3 <= nt)      asm volatile("s_waitcnt vmcnt(12)" ::: "memory");
  else if (t + 2 == nt) asm volatile("s_waitcnt vmcnt(6)" ::: "memory");
  else                  asm volatile("s_waitcnt vmcnt(0)" ::: "memory");
}

enum { EPI_BF = 0, EPI_SILU_BF = 1, EPI_RES = 2 };

// ---------------------------------------------------------------------------
// Pipelined wide-N GEMM: 512 thr, BM=256 BN=128 BK=64, 3-stage LDS.
// ---------------------------------------------------------------------------
template<int EPI>
__global__ __launch_bounds__(512) void gemm8(
    const bf16_t* __restrict__ A, const bf16_t* __restrict__ B,
    const float* __restrict__ bias, const float* __restrict__ res,
    void* __restrict__ Cv,
    int lda, int ldb, int ldc, int Kd, float scale)
{
  __shared__ __align__(16) bf16_t As[3][256 * 64];   // 96 KB
  __shared__ __align__(16) bf16_t Bs[3][128 * 64];   // 48 KB

  const int gx = gridDim.x;
  const int nwg = gx * gridDim.y;
  int wg = blockIdx.y * gx + blockIdx.x;
  wg = (wg & 7) * (nwg >> 3) + (wg >> 3);
  const int m0 = (wg / gx) * 256, n0 = (wg % gx) * 128;

  const int tid = threadIdx.x;
  const int wid = tid >> 6, lane = tid & 63;
  const int lrow = lane & 15, lk = lane >> 4;
  const int wm = (wid >> 1) * 64, wn = (wid & 1) * 64;   // 4x2 wave grid
  const int r = tid >> 3;
  const int cs = (((tid & 7) ^ (r & 7)) << 3);
  const int fsw = lrow & 7;

  auto stage = [&](int kt, int s) {
    const bf16_t* ga = A + (long)(m0 + r) * lda + (kt * 64 + cs);
    const bf16_t* gb = B + (long)(n0 + r) * ldb + (kt * 64 + cs);
    bf16_t* as = &As[s][0];
    bf16_t* bs = &Bs[s][0];
#pragma unroll
    for (int it = 0; it < 4; ++it)
      gload16(ga + (long)it * 64 * lda, as + tid * 8 + it * 4096);
#pragma unroll
    for (int it = 0; it < 2; ++it)
      gload16(gb + (long)it * 64 * ldb, bs + tid * 8 + it * 4096);
  };

  f32x4 acc[4][4] = {};
  const int nt = Kd / 64;

  stage(0, 0);
  stage(1, 1);
  stage(2, 2);

  int s = 0;
  for (int t = 0; t < nt; ++t) {
    pipe_wait(t, nt);
    asm volatile("s_barrier" ::: "memory");

    bf16x8 av[2][4], bv[2][4];
    const bf16_t* as = &As[s][0];
    const bf16_t* bs = &Bs[s][0];
#pragma unroll
    for (int kk = 0; kk < 2; ++kk) {
#pragma unroll
      for (int i = 0; i < 4; ++i)
        av[kk][i] = *(const bf16x8*)&as[(wm + i * 16 + lrow) * 64 + ((((kk << 2) + lk) ^ fsw) << 3)];
#pragma unroll
      for (int j = 0; j < 4; ++j)
        bv[kk][j] = *(const bf16x8*)&bs[(wn + j * 16 + lrow) * 64 + ((((kk << 2) + lk) ^ fsw) << 3)];
    }
    __builtin_amdgcn_s_setprio(1);
#pragma unroll
    for (int kk = 0; kk < 2; ++kk)
#pragma unroll
      for (int i = 0; i < 4; ++i)
#pragma unroll
        for (int j = 0; j < 4; ++j)
          acc[i][j] = __builtin_amdgcn_mfma_f32_16x16x32_bf16(av[kk][i], bv[kk][j], acc[i][j], 0, 0, 0);
    __builtin_amdgcn_s_setprio(0);

    asm volatile("s_barrier" ::: "memory");
    if (t + 3 < nt) stage(t + 3, s);
    s = (s == 2) ? 0 : s + 1;
  }

#pragma unroll
  for (int j = 0; j < 4; ++j) {
    int col = n0 + wn + j * 16 + lrow;
    float bb = bias ? bias[col] : 0.0f;
#pragma unroll
    for (int i = 0; i < 4; ++i) {
#pragma unroll
      for (int rr = 0; rr < 4; ++rr) {
        int row = m0 + wm + i * 16 + lk * 4 + rr;
        long idx = (long)row * ldc + col;
        float v = (acc[i][j][rr] + bb) * scale;
        if constexpr (EPI == EPI_SILU_BF) v *= sigm(v);
        if constexpr (EPI == EPI_RES) {
          ((float*)Cv)[idx] = res[idx] + v;
        } else {
          ((bf16_t*)Cv)[idx] = (bf16_t)v;
        }
      }
    }
  }
}

// ---------------------------------------------------------------------------
// Pipelined narrow-N GEMM: 256 thr, BM=64 BN=128 BK=64, 3-stage LDS (72 KB,
// 2 blocks/CU = 8 waves/CU). Same counted-vmcnt schedule (6 loads/stage).
// ---------------------------------------------------------------------------
template<int EPI>
__global__ __launch_bounds__(256) void gemm4p(
    const bf16_t* __restrict__ A, const bf16_t* __restrict__ B,
    const float* __restrict__ bias, const float* __restrict__ res,
    void* __restrict__ Cv,
    int lda, int ldb, int ldc, int Kd, float scale)
{
  __shared__ __align__(16) bf16_t As[3][64 * 64];    // 24 KB
  __shared__ __align__(16) bf16_t Bs[3][128 * 64];   // 48 KB

  const int gx = gridDim.x;
  const int nwg = gx * gridDim.y;
  int wg = blockIdx.y * gx + blockIdx.x;
  wg = (wg & 7) * (nwg >> 3) + (wg >> 3);
  const int m0 = (wg / gx) * 64, n0 = (wg % gx) * 128;

  const int tid = threadIdx.x;
  const int wid = tid >> 6, lane = tid & 63;
  const int lrow = lane & 15, lk = lane >> 4;
  const int wm = (wid >> 1) * 32, wn = (wid & 1) * 64;   // 2x2 wave grid
  const int r = tid >> 3;
  const int cs = (((tid & 7) ^ (r & 7)) << 3);
  const int fsw = lrow & 7;

  auto stage = [&](int kt, int s) {
    const bf16_t* ga = A + (long)(m0 + r) * lda + (kt * 64 + cs);
    const bf16_t* gb = B + (long)(n0 + r) * ldb + (kt * 64 + cs);
#pragma unroll
    for (int it = 0; it < 2; ++it)
      gload16(ga + (long)it * 32 * lda, &As[s][tid * 8 + it * 2048]);
#pragma unroll
    for (int it = 0; it < 4; ++it)
      gload16(gb + (long)it * 32 * ldb, &Bs[s][tid * 8 + it * 2048]);
  };

  f32x4 acc[2][4] = {};
  const int nt = Kd / 64;

  stage(0, 0);
  stage(1, 1);
  stage(2, 2);

  int s = 0;
  for (int t = 0; t < nt; ++t) {
    pipe_wait(t, nt);
    asm volatile("s_barrier" ::: "memory");

    bf16x8 av[2][2], bv[2][4];
    const bf16_t* as = &As[s][0];
    const bf16_t* bs = &Bs[s][0];
#pragma unroll
    for (int kk = 0; kk < 2; ++kk) {
#pragma unroll
      for (int i = 0; i < 2; ++i)
        av[kk][i] = *(const bf16x8*)&as[(wm + i * 16 + lrow) * 64 + ((((kk << 2) + lk) ^ fsw) << 3)];
#pragma unroll
      for (int j = 0; j < 4; ++j)
        bv[kk][j] = *(const bf16x8*)&bs[(wn + j * 16 + lrow) * 64 + ((((kk << 2) + lk) ^ fsw) << 3)];
    }
    __builtin_amdgcn_s_setprio(1);
#pragma unroll
    for (int kk = 0; kk < 2; ++kk)
#pragma unroll
      for (int i = 0; i < 2; ++i)
#pragma unroll
        for (int j = 0; j < 4; ++j)
          acc[i][j] = __builtin_amdgcn_mfma_f32_16x16x32_bf16(av[kk][i], bv[kk][j], acc[i][j], 0, 0, 0);
    __builtin_amdgcn_s_setprio(0);

    asm volatile("s_barrier" ::: "memory");
    if (t + 3 < nt) stage(t + 3, s);
    s = (s == 2) ? 0 : s + 1;
  }

#pragma unroll
  for (int j = 0; j < 4; ++j) {
    int col = n0 + wn + j * 16 + lrow;
    float bb = bias ? bias[col] : 0.0f;
#pragma unroll
    for (int i = 0; i < 2; ++i) {
#pragma unroll
      for (int rr = 0; rr < 4; ++rr) {
        int row = m0 + wm + i * 16 + lk * 4 + rr;
        long idx = (long)row * ldc + col;
        float v = (acc[i][j][rr] + bb) * scale;
        if constexpr (EPI == EPI_SILU_BF) v *= sigm(v);
        if constexpr (EPI == EPI_RES) {
          ((float*)Cv)[idx] = res[idx] + v;
        } else {
          ((bf16_t*)Cv)[idx] = (bf16_t)v;
        }
      }
    }
  }
}

// ---------------------------------------------------------------------------
// Flash attention (full KV). Block = 128 q-rows of one (b,h), 4 waves x
// 32 q-rows. K/V LDS double-buffered (static offsets). Softmax in-register:
// tree max + permlane32_swap; row-sum via ones-row MFMA; exp2; defer-max.
// ---------------------------------------------------------------------------
__global__ __launch_bounds__(256) void fattn_k(
    const bf16_t* __restrict__ QK,   // [B*T][1536], Q at 0, K at 512
    const bf16_t* __restrict__ VT,   // [B*H][64][2048]
    bf16_t* __restrict__ O)          // [B*T][512]
{
  __shared__ __align__(16) bf16_t S[16384];      // 32 KB

  const int tid = threadIdx.x;
  const int w = tid >> 6, lane = tid & 63;
  const int l31 = lane & 31, hi = lane >> 5;
  const int q0 = blockIdx.x * 128;
  const int bh = blockIdx.y, b = bh >> 3, h = bh & 7;

  const int r8 = tid >> 3;
  const int csw = ((tid & 7) ^ (r8 & 7)) << 3;
  const int fswl = l31 & 7;

  const bf16_t* Qg = QK + ((long)b * CT + q0) * 1536 + h * 64;
  const bf16_t* Kg = QK + (long)b * CT * 1536 + 512 + h * 64;
  const bf16_t* Vg = VT + (long)bh * 64 * 2048;

#pragma unroll
  for (int it = 0; it < 4; ++it)
    gload16(Qg + (long)(r8 + it * 32) * 1536 + csw, &S[8192 + tid * 8 + it * 2048]);
#pragma unroll
  for (int it = 0; it < 2; ++it)
    gload16(Kg + (long)(r8 + it * 32) * 1536 + csw, &S[tid * 8 + it * 2048]);
#pragma unroll
  for (int it = 0; it < 2; ++it)
    gload16(Vg + (long)(r8 + it * 32) * 2048 + csw, &S[4096 + tid * 8 + it * 2048]);
  __syncthreads();

  bf16x8 qb[4];
#pragma unroll
  for (int m = 0; m < 4; ++m)
    qb[m] = *(const bf16x8*)&S[8192 + (w * 32 + l31) * 64 + (((m * 2 + hi) ^ fswl) << 3)];
  __syncthreads();

  const u16x8 onesu = {0x3F80, 0x3F80, 0x3F80, 0x3F80, 0x3F80, 0x3F80, 0x3F80, 0x3F80};
  const bf16x8 onesf = __builtin_bit_cast(bf16x8, onesu);

  f32x16 o0 = {}, o1 = {}, lacc = {};
  float mrun = -3.0e38f;

#define FA_BODY(CURK, CURV, NXTK, NXTV, KV0, STG)                               \
  {                                                                             \
    if (STG) {                                                                  \
      const int nxt = (KV0) + 64;                                               \
      _Pragma("unroll")                                                         \
      for (int it = 0; it < 2; ++it)                                            \
        gload16(Kg + (long)(nxt + r8 + it * 32) * 1536 + csw,                   \
                &S[(NXTK) + tid * 8 + it * 2048]);                              \
      _Pragma("unroll")                                                         \
      for (int it = 0; it < 2; ++it)                                            \
        gload16(Vg + (long)(r8 + it * 32) * 2048 + nxt + csw,                   \
                &S[(NXTV) + tid * 8 + it * 2048]);                              \
    }                                                                           \
    bf16x8 ka[2][4];                                                            \
    _Pragma("unroll")                                                           \
    for (int j = 0; j < 2; ++j)                                                 \
      _Pragma("unroll")                                                         \
      for (int m = 0; m < 4; ++m)                                               \
        ka[j][m] = *(const bf16x8*)&S[(CURK) + (j * 32 + l31) * 64 +            \
                                      (((m * 2 + hi) ^ fswl) << 3)];            \
    f32x16 s0 = {}, s1 = {};                                                    \
    __builtin_amdgcn_s_setprio(1);                                              \
    _Pragma("unroll")                                                           \
    for (int m = 0; m < 4; ++m) {                                               \
      s0 = __builtin_amdgcn_mfma_f32_32x32x16_bf16(ka[0][m], qb[m], s0, 0, 0, 0); \
      s1 = __builtin_amdgcn_mfma_f32_32x32x16_bf16(ka[1][m], qb[m], s1, 0, 0, 0); \
    }                                                                           \
    __builtin_amdgcn_s_setprio(0);                                              \
    float tm[16];                                                               \
    _Pragma("unroll")                                                           \
    for (int rr = 0; rr < 16; ++rr) tm[rr] = fmaxf(s0[rr], s1[rr]);             \
    _Pragma("unroll")                                                           \
    for (int stp = 8; stp; stp >>= 1)                                           \
      _Pragma("unroll")                                                         \
      for (int rr = 0; rr < stp; ++rr) tm[rr] = fmaxf(tm[rr], tm[rr + stp]);    \
    float pm = tm[0];                                                           \
    { float pa = pm, pb = pm;                                                   \
      asm("v_permlane32_swap_b32 %0, %1" : "+v"(pa), "+v"(pb));                 \
      pm = fmaxf(pa, pb); }                                                     \
    if (!__all(pm <= mrun + 8.0f)) {                                            \
      float mn = fmaxf(mrun, pm);                                               \
      float al = exp2f(mrun - mn);                                              \
      mrun = mn;                                                                \
      lacc[0] *= al;                                                            \
      _Pragma("unroll")                                                         \
      for (int rr = 0; rr < 16; ++rr) { o0[rr] *= al; o1[rr] *= al; }           \
    }                                                                           \
    _Pragma("unroll")                                                           \
    for (int rr = 0; rr < 16; ++rr) s0[rr] = exp2f(s0[rr] - mrun);              \
    _Pragma("unroll")                                                           \
    for (int rr = 0; rr < 16; ++rr) s1[rr] = exp2f(s1[rr] - mrun);              \
    bf16x8 pw[4];                                                               \
    _Pragma("unroll")                                                           \
    for (int jk = 0; jk < 4; ++jk) {                                            \
      float e0, e1, e2, e3, e4, e5, e6, e7;                                     \
      if (jk == 0) { e0=s0[0];e1=s0[1];e2=s0[2];e3=s0[3];e4=s0[4];e5=s0[5];e6=s0[6];e7=s0[7]; }        \
      else if (jk == 1) { e0=s0[8];e1=s0[9];e2=s0[10];e3=s0[11];e4=s0[12];e5=s0[13];e6=s0[14];e7=s0[15]; } \
      else if (jk == 2) { e0=s1[0];e1=s1[1];e2=s1[2];e3=s1[3];e4=s1[4];e5=s1[5];e6=s1[6];e7=s1[7]; }   \
      else { e0=s1[8];e1=s1[9];e2=s1[10];e3=s1[11];e4=s1[12];e5=s1[13];e6=s1[14];e7=s1[15]; }          \
      unsigned a0 = cvtpk(e0, e1), a1 = cvtpk(e2, e3);                          \
      unsigned b0 = cvtpk(e4, e5), b1 = cvtpk(e6, e7);                          \
      asm("v_permlane32_swap_b32 %0, %1" : "+v"(a0), "+v"(b0));                 \
      asm("v_permlane32_swap_b32 %0, %1" : "+v"(a1), "+v"(b1));                 \
      u32x4 t; t[0] = a0; t[1] = a1; t[2] = b0; t[3] = b1;                      \
      pw[jk] = __builtin_bit_cast(bf16x8, t);                                   \
    }                                                                           \
    bf16x8 va[2][4];                                                            \
    _Pragma("unroll")                                                           \
    for (int n = 0; n < 2; ++n)                                                 \
      _Pragma("unroll")                                                         \
      for (int jk = 0; jk < 4; ++jk)                                            \
        va[n][jk] = *(const bf16x8*)&S[(CURV) + (n * 32 + l31) * 64 +           \
                                       (((jk * 2 + hi) ^ fswl) << 3)];          \
    __builtin_amdgcn_s_setprio(1);                                              \
    _Pragma("unroll")                                                           \
    for (int jk = 0; jk < 4; ++jk) {                                            \
      o0 = __builtin_amdgcn_mfma_f32_32x32x16_bf16(va[0][jk], pw[jk], o0, 0, 0, 0); \
      o1 = __builtin_amdgcn_mfma_f32_32x32x16_bf16(va[1][jk], pw[jk], o1, 0, 0, 0); \
      lacc = __builtin_amdgcn_mfma_f32_32x32x16_bf16(onesf, pw[jk], lacc, 0, 0, 0); \
    }                                                                           \
    __builtin_amdgcn_s_setprio(0);                                              \
    __syncthreads();                                                            \
  }

  for (int kv0 = 0; kv0 < CT; kv0 += 128) {
    FA_BODY(0, 4096, 8192, 12288, kv0, 1)
    FA_BODY(8192, 12288, 0, 4096, kv0 + 64, (kv0 + 128 < CT))
  }
#undef FA_BODY

  float rl = 1.0f / lacc[0];
  bf16_t* Op = O + ((long)b * CT + q0 + w * 32 + l31) * CD + h * 64;
#pragma unroll
  for (int n = 0; n < 2; ++n) {
#pragma unroll
    for (int m = 0; m < 4; ++m) {
      u16x4 pk4;
#pragma unroll
      for (int e = 0; e < 4; ++e)
        pk4[e] = f2bf((n ? o1[m * 4 + e] : o0[m * 4 + e]) * rl);
      *(u16x4*)(Op + n * 32 + m * 8 + hi * 4) = pk4;
    }
  }
}

// ---------------------------------------------------------------------------
// Weight convert+transpose: w[K][N] f32 -> o[N][K] bf16. 64x64 tiles.
// ---------------------------------------------------------------------------
__global__ __launch_bounds__(256) void wtrans_k(
    const float* __restrict__ w, u16* __restrict__ o, int Kd, int N)
{
  __shared__ u16 lt[64][72];
  const int k0 = blockIdx.y * 64, n0 = blockIdx.x * 64;
  const int tid = threadIdx.x;
#pragma unroll
  for (int it = 0; it < 4; ++it) {
    int kk = (tid >> 4) + it * 16, nn = (tid & 15) * 4;
    float4 f = *(const float4*)(w + (long)(k0 + kk) * N + n0 + nn);
    lt[kk][nn + 0] = f2bf(f.x); lt[kk][nn + 1] = f2bf(f.y);
    lt[kk][nn + 2] = f2bf(f.z); lt[kk][nn + 3] = f2bf(f.w);
  }
  __syncthreads();
#pragma unroll
  for (int it = 0; it < 2; ++it) {
    int nn = (tid >> 3) + it * 32, kk = (tid & 7) * 8;
    u16x8 pk;
#pragma unroll
    for (int e = 0; e < 8; ++e) pk[e] = lt[kk + e][nn];
    *(u16x8*)(o + (long)(n0 + nn) * Kd + k0 + kk) = pk;
  }
}

// V columns of bufQKV -> VT[bh][d][t]
__global__ __launch_bounds__(256) void vtrans_k(
    const u16* __restrict__ v, u16* __restrict__ vt)
{
  __shared__ u16 lt[64][72];
  const int bh = blockIdx.y, b = bh >> 3, h = bh & 7;
  const int t0 = blockIdx.x * 64;
  const int tid = threadIdx.x;
#pragma unroll
  for (int it = 0; it < 2; ++it) {
    int tt = (tid >> 3) + it * 32, dd = (tid & 7) * 8;
    u16x8 vv = *(const u16x8*)(v + ((long)b * CT + t0 + tt) * 1536 + 1024 + h * 64 + dd);
#pragma unroll
    for (int e = 0; e < 8; ++e) lt[tt][dd + e] = vv[e];
  }
  __syncthreads();
#pragma unroll
  for (int it = 0; it < 2; ++it) {
    int dd = (tid >> 3) + it * 32, tt = (tid & 7) * 8;
    u16x8 pk;
#pragma unroll
    for (int e = 0; e < 8; ++e) pk[e] = lt[tt + e][dd];
    *(u16x8*)(vt + ((long)bh * 64 + dd) * CT + t0 + tt) = pk;
  }
}

// dw_w[512][31] f32 -> wT[31][512] f32
__global__ void dwt_k(const float* __restrict__ w, float* __restrict__ o)
{
  int i = blockIdx.x * 256 + threadIdx.x;
  if (i < 512 * 31) { int c = i / 31, k = i % 31; o[k * 512 + c] = w[i]; }
}

// ---------------------------------------------------------------------------
// LayerNorm over D=512, one block per row.
// ---------------------------------------------------------------------------
template<int OBF>
__global__ __launch_bounds__(256) void ln_k(
    const float* __restrict__ in, const float* __restrict__ g,
    const float* __restrict__ b, void* __restrict__ out)
{
  __shared__ float rs[4], rq[4];
  const long row = blockIdx.x;
  const int tid = threadIdx.x;
  float2 v = ((const float2*)(in + row * CD))[tid];
  float s = v.x + v.y, q = v.x * v.x + v.y * v.y;
#pragma unroll
  for (int o = 32; o; o >>= 1) { s += __shfl_xor(s, o); q += __shfl_xor(q, o); }
  if ((tid & 63) == 0) { rs[tid >> 6] = s; rq[tid >> 6] = q; }
  __syncthreads();
  s = rs[0] + rs[1] + rs[2] + rs[3];
  q = rq[0] + rq[1] + rq[2] + rq[3];
  float mean = s * (1.0f / CD);
  float var = q * (1.0f / CD) - mean * mean;
  float rstd = rsqrtf(var + 1e-5f);
  float2 gg = ((const float2*)g)[tid];
  float2 bb = ((const float2*)b)[tid];
  float ox = (v.x - mean) * rstd * gg.x + bb.x;
  float oy = (v.y - mean) * rstd * gg.y + bb.y;
  if (OBF) {
    unsigned pk = ((unsigned)f2bf(oy) << 16) | f2bf(ox);
    ((unsigned*)out)[row * 256 + tid] = pk;
  } else {
    ((float2*)out)[row * 256 + tid] = make_float2(ox, oy);
  }
}

__global__ void rope_table_k(float* __restrict__ cosT, float* __restrict__ sinT)
{
  int tid = blockIdx.x * 256 + threadIdx.x;     // T*32
  int t = tid >> 5, i = tid & 31;
  float freq = __expf(-(float)i * (9.210340371976184f / 32.0f));
  float ang = (float)t * freq;
  cosT[tid] = cosf(ang);
  sinT[tid] = sinf(ang);
}

// In-place RoPE on fused QKV (Q cols 0..511 scaled by 0.125*log2e, K 512..1023).
__global__ __launch_bounds__(256) void rope_k(
    unsigned* __restrict__ qkv,
    const float* __restrict__ cosT, const float* __restrict__ sinT)
{
  const float SC = 0.125f * 1.44269504089f;
  long p = (long)blockIdx.x * 256 + threadIdx.x;
  int pr = (int)(p & 255);
  long row = p >> 8;
  int t = (int)(row & (CT - 1));
  int h = pr >> 5, i = pr & 31;
  float c = cosT[t * 32 + i], s = sinT[t * 32 + i];
  unsigned* base = qkv + row * 768 + h * 32 + i;
  unsigned v = base[0];
  float xe = bf2f((u16)v), xo = bf2f((u16)(v >> 16));
  base[0] = ((unsigned)f2bf((xe * s + xo * c) * SC) << 16) | f2bf((xe * c - xo * s) * SC);
  v = base[256];
  xe = bf2f((u16)v); xo = bf2f((u16)(v >> 16));
  base[256] = ((unsigned)f2bf(xe * s + xo * c) << 16) | f2bf(xe * c - xo * s);
}

// GLU
__global__ __launch_bounds__(256) void glu_k(
    const u16* __restrict__ t, u16* __restrict__ out)
{
  long idx = (long)blockIdx.x * 256 + threadIdx.x;
  long row = idx >> 7;
  int c4 = (int)(idx & 127) * 4;
  u16x4 a = *(const u16x4*)(t + row * 1024 + c4);
  u16x4 b = *(const u16x4*)(t + row * 1024 + 512 + c4);
  u16x4 o;
#pragma unroll
  for (int e = 0; e < 4; ++e) o[e] = f2bf(bf2f(a[e]) * sigm(bf2f(b[e])));
  *(u16x4*)(out + row * CD + c4) = o;
}

// Depthwise conv1d: bf16 in, bf16 out. 8 t-outputs x 4 channels/thread.
__global__ __launch_bounds__(256) void dwconv_k(
    const u16* __restrict__ in, const float* __restrict__ wT,
    const float* __restrict__ wb, u16* __restrict__ out)
{
  long idx = (long)blockIdx.x * 256 + threadIdx.x;
  int c4 = (int)(idx & 127) * 4;
  int t0 = (int)((idx >> 7) & 255) * 8;
  int b = (int)(idx >> 15);
  const u16* base = in + (long)b * CT * CD;
  float4 bias = *(const float4*)(wb + c4);
  float4 acc[8];
#pragma unroll
  for (int t = 0; t < 8; ++t) acc[t] = bias;
#pragma unroll
  for (int j = 0; j < 38; ++j) {
    int tr = t0 + j - 15;
    float4 row = make_float4(0.f, 0.f, 0.f, 0.f);
    if (tr >= 0 && tr < CT) {
      u16x4 rv = *(const u16x4*)(base + (long)tr * CD + c4);
      row = make_float4(bf2f(rv[0]), bf2f(rv[1]), bf2f(rv[2]), bf2f(rv[3]));
    }
#pragma unroll
    for (int t = 0; t < 8; ++t) {
      int k = j - t;
      if (k >= 0 && k < CK) {
        float4 w4 = *(const float4*)(wT + k * CD + c4);
        acc[t].x += row.x * w4.x; acc[t].y += row.y * w4.y;
        acc[t].z += row.z * w4.z; acc[t].w += row.w * w4.w;
      }
    }
  }
#pragma unroll
  for (int t = 0; t < 8; ++t) {
    u16x4 pk;
    pk[0] = f2bf(acc[t].x); pk[1] = f2bf(acc[t].y);
    pk[2] = f2bf(acc[t].z); pk[3] = f2bf(acc[t].w);
    *(u16x4*)(out + ((long)b * CT + t0 + t) * CD + c4) = pk;
  }
}

__global__ __launch_bounds__(256) void bn_part_k(
    const u16* __restrict__ in, float* __restrict__ psum, float* __restrict__ psq)
{
  const int blk = blockIdx.x;        // 256
  const int tid = threadIdx.x;
  const int c0 = tid, c1 = tid + 256;
  const int rows = CBT / 256;
  const u16* base = in + (long)blk * rows * CD;
  float s0 = 0, q0 = 0, s1 = 0, q1 = 0;
  for (int r = 0; r < rows; ++r) {
    float v0 = bf2f(base[(long)r * CD + c0]); s0 += v0; q0 += v0 * v0;
    float v1 = bf2f(base[(long)r * CD + c1]); s1 += v1; q1 += v1 * v1;
  }
  psum[blk * CD + c0] = s0; psq[blk * CD + c0] = q0;
  psum[blk * CD + c1] = s1; psq[blk * CD + c1] = q1;
}

__global__ __launch_bounds__(256) void bn_fin_k(
    const float* __restrict__ psum, const float* __restrict__ psq,
    float* __restrict__ stat)
{
  int c = blockIdx.x * 256 + threadIdx.x;
  float s = 0, q = 0;
  for (int i = 0; i < 256; ++i) { s += psum[i * CD + c]; q += psq[i * CD + c]; }
  float mean = s * (1.0f / CBT);
  float var = q * (1.0f / CBT) - mean * mean;
  stat[c] = mean;
  stat[CD + c] = rsqrtf(var + 1e-5f);
}

__global__ __launch_bounds__(256) void bn_app_k(
    const u16* __restrict__ h, const float* __restrict__ stat,
    const float* __restrict__ g, const float* __restrict__ b,
    u16* __restrict__ out)
{
  long idx = (long)blockIdx.x * 256 + threadIdx.x;
  int c = (int)(idx & 511);
  float v = (bf2f(h[idx]) - stat[c]) * stat[CD + c] * g[c] + b[c];
  v = v * sigm(v);
  out[idx] = f2bf(v);
}

// ---------------------------------------------------------------------------
// Host launcher
// ---------------------------------------------------------------------------
extern "C" void kernel_launch(void* const* d_in, const int* in_sizes, int n_in,
                              void* d_out, int out_size, void* d_ws, size_t ws_size,
                              hipStream_t stream)
{
  const float* x        = (const float*)d_in[0];
  const float* ff1_lng  = (const float*)d_in[1];
  const float* ff1_lnb  = (const float*)d_in[2];
  const float* ff1_w1   = (const float*)d_in[3];
  const float* ff1_b1   = (const float*)d_in[4];
  const float* ff1_w2   = (const float*)d_in[5];
  const float* ff1_b2   = (const float*)d_in[6];
  const float* attn_lng = (const float*)d_in[7];
  const float* attn_lnb = (const float*)d_in[8];
  const float* wq       = (const float*)d_in[9];
  const float* wk       = (const float*)d_in[10];
  const float* wv       = (const float*)d_in[11];
  const float* wo       = (const float*)d_in[12];
  const float* conv_lng = (const float*)d_in[13];
  const float* conv_lnb = (const float*)d_in[14];
  const float* pw1_w    = (const float*)d_in[15];
  const float* pw1_b    = (const float*)d_in[16];
  const float* dw_w     = (const float*)d_in[17];
  const float* dw_b     = (const float*)d_in[18];
  const float* bn_g     = (const float*)d_in[19];
  const float* bn_b     = (const float*)d_in[20];
  const float* pw2_w    = (const float*)d_in[21];
  const float* pw2_b    = (const float*)d_in[22];
  const float* ff2_lng  = (const float*)d_in[23];
  const float* ff2_lnb  = (const float*)d_in[24];
  const float* ff2_w1   = (const float*)d_in[25];
  const float* ff2_b1   = (const float*)d_in[26];
  const float* ff2_w2   = (const float*)d_in[27];
  const float* ff2_b2   = (const float*)d_in[28];
  const float* out_lng  = (const float*)d_in[29];
  const float* out_lnb  = (const float*)d_in[30];
  float* out = (float*)d_out;

  char* p = (char*)d_ws;
  auto alloc = [&](size_t bytes) { char* r = p; p += (bytes + 255) & ~(size_t)255; return r; };
  float*  bufX   = (float*)alloc((size_t)CBT * CD * 4);
  bf16_t* bufH   = (bf16_t*)alloc((size_t)CBT * CD * 2);
  bf16_t* bufQKV = (bf16_t*)alloc((size_t)CBT * 1536 * 2);
  bf16_t* bufO   = (bf16_t*)alloc((size_t)CBT * CD * 2);
  bf16_t* bufVT  = (bf16_t*)alloc((size_t)CBT * CD * 2);
  bf16_t* bufP   = (bf16_t*)alloc((size_t)CBT * CINNER * 2);
  bf16_t* w_ff1a = (bf16_t*)alloc((size_t)CD * CINNER * 2);
  bf16_t* w_ff1b = (bf16_t*)alloc((size_t)CD * CINNER * 2);
  bf16_t* w_qkv  = (bf16_t*)alloc((size_t)CD * 1536 * 2);
  bf16_t* w_o    = (bf16_t*)alloc((size_t)CD * CD * 2);
  bf16_t* w_pw1  = (bf16_t*)alloc((size_t)CD * 2 * CD * 2);
  bf16_t* w_pw2  = (bf16_t*)alloc((size_t)CD * CD * 2);
  bf16_t* w_ff2a = (bf16_t*)alloc((size_t)CD * CINNER * 2);
  bf16_t* w_ff2b = (bf16_t*)alloc((size_t)CD * CINNER * 2);
  float* dwT  = (float*)alloc((size_t)CK * CD * 4);
  float* cosT = (float*)alloc((size_t)CT * 32 * 4);
  float* sinT = (float*)alloc((size_t)CT * 32 * 4);
  float* psum = (float*)alloc((size_t)256 * CD * 4);
  float* psq  = (float*)alloc((size_t)256 * CD * 4);
  float* stat = (float*)alloc((size_t)2 * CD * 4);

  const dim3 blk(256);
  const dim3 blk8(512);

  wtrans_k<<<dim3(CINNER / 64, CD / 64), blk, 0, stream>>>(ff1_w1, (u16*)w_ff1a, CD, CINNER);
  wtrans_k<<<dim3(CD / 64, CINNER / 64), blk, 0, stream>>>(ff1_w2, (u16*)w_ff1b, CINNER, CD);
  wtrans_k<<<dim3(CD / 64, CD / 64), blk, 0, stream>>>(wq, (u16*)w_qkv, CD, CD);
  wtrans_k<<<dim3(CD / 64, CD / 64), blk, 0, stream>>>(wk, (u16*)(w_qkv + (size_t)512 * CD), CD, CD);
  wtrans_k<<<dim3(CD / 64, CD / 64), blk, 0, stream>>>(wv, (u16*)(w_qkv + (size_t)1024 * CD), CD, CD);
  wtrans_k<<<dim3(CD / 64, CD / 64), blk, 0, stream>>>(wo, (u16*)w_o, CD, CD);
  wtrans_k<<<dim3(2 * CD / 64, CD / 64), blk, 0, stream>>>(pw1_w, (u16*)w_pw1, CD, 2 * CD);
  wtrans_k<<<dim3(CD / 64, CD / 64), blk, 0, stream>>>(pw2_w, (u16*)w_pw2, CD, CD);
  wtrans_k<<<dim3(CINNER / 64, CD / 64), blk, 0, stream>>>(ff2_w1, (u16*)w_ff2a, CD, CINNER);
  wtrans_k<<<dim3(CD / 64, CINNER / 64), blk, 0, stream>>>(ff2_w2, (u16*)w_ff2b, CINNER, CD);
  dwt_k<<<dim3(62), blk, 0, stream>>>(dw_w, dwT);
  rope_table_k<<<dim3(CT * 32 / 256), blk, 0, stream>>>(cosT, sinT);

  // ---- FF1 ----
  ln_k<1><<<dim3(CBT), blk, 0, stream>>>(x, ff1_lng, ff1_lnb, bufH);
  gemm8<EPI_SILU_BF><<<dim3(16, 32), blk8, 0, stream>>>(
      bufH, w_ff1a, ff1_b1, nullptr, bufP, CD, CD, CINNER, CD, 1.0f);
  gemm4p<EPI_RES><<<dim3(4, 128), blk, 0, stream>>>(
      bufP, w_ff1b, ff1_b2, x, bufX, CINNER, CINNER, CD, CINNER, 0.5f);

  // ---- Attention ----
  ln_k<1><<<dim3(CBT), blk, 0, stream>>>(bufX, attn_lng, attn_lnb, bufH);
  gemm8<EPI_BF><<<dim3(12, 32), blk8, 0, stream>>>(
      bufH, w_qkv, nullptr, nullptr, bufQKV, CD, CD, 1536, CD, 1.0f);
  rope_k<<<dim3(CB * CT), blk, 0, stream>>>((unsigned*)bufQKV, cosT, sinT);
  vtrans_k<<<dim3(CT / 64, CB * CH), blk, 0, stream>>>((const u16*)bufQKV, (u16*)bufVT);
  fattn_k<<<dim3(CT / 128, CB * CH), blk, 0, stream>>>(bufQKV, bufVT, bufO);
  gemm4p<EPI_RES><<<dim3(4, 128), blk, 0, stream>>>(
      bufO, w_o, nullptr, bufX, bufX, CD, CD, CD, CD, 1.0f);

  // ---- Conv module ----
  ln_k<1><<<dim3(CBT), blk, 0, stream>>>(bufX, conv_lng, conv_lnb, bufH);
  gemm8<EPI_BF><<<dim3(8, 32), blk8, 0, stream>>>(
      bufH, w_pw1, pw1_b, nullptr, bufP, CD, CD, 2 * CD, CD, 1.0f);
  glu_k<<<dim3(CBT * 128 / 256), blk, 0, stream>>>((const u16*)bufP, (u16*)bufH);
  dwconv_k<<<dim3(512), blk, 0, stream>>>((const u16*)bufH, dwT, dw_b, (u16*)bufO);
  bn_part_k<<<dim3(256), blk, 0, stream>>>((const u16*)bufO, psum, psq);
  bn_fin_k<<<dim3(2), blk, 0, stream>>>(psum, psq, stat);
  bn_app_k<<<dim3(CBT * CD / 256), blk, 0, stream>>>((const u16*)bufO, stat, bn_g, bn_b, (u16*)bufH);
  gemm4p<EPI_RES><<<dim3(4, 128), blk, 0, stream>>>(
      bufH, w_pw2, pw2_b, bufX, bufX, CD, CD, CD, CD, 1.0f);

  // ---- FF2 ----
  ln_k<1><<<dim3(CBT), blk, 0, stream>>>(bufX, ff2_lng, ff2_lnb, bufH);
  gemm8<EPI_SILU_BF><<<dim3(16, 32), blk8, 0, stream>>>(
      bufH, w_ff2a, ff2_b1, nullptr, bufP, CD, CD, CINNER, CD, 1.0f);
  gemm4p<EPI_RES><<<dim3(4, 128), blk, 0, stream>>>(
      bufP, w_ff2b, ff2_b2, bufX, bufX, CINNER, CINNER, CD, CINNER, 0.5f);

  // ---- Output LN ----
  ln_k<0><<<dim3(CBT), blk, 0, stream>>>(bufX, out_lng, out_lnb, out);

  (void)in_sizes; (void)n_in; (void)out_size; (void)ws_size;
}

// Round 11
// 389.107 us; speedup vs baseline: 1.0467x; 1.0433x over previous
//
#include <hip/hip_runtime.h>

// ---------------------------------------------------------------------------
// STTConformerBlock: B=4 T=2048 D=512 H=8 DH=64 INNER=2048 K=31, f32 I/O.
// gemm8 = 512-thr 256x128 pipelined GEMM (3-stage LDS, counted vmcnt,
//         raw s_barrier, XCD swizzle) for wide-N; EPI_GLU variant fuses the
//         GLU gate via interleaved pw1 weights.
// gemm_bf = 256-thr 64x128 BK=128 2-phase GEMM for narrow-N (proven fastest).
// Flash attention: swapped-QK^T 32x32 MFMA, LDS K/V dbuf, in-register softmax,
// row-sum via ones-row MFMA, exp2 domain, defer-max.
// ---------------------------------------------------------------------------

typedef float  f32x4   __attribute__((ext_vector_type(4)));
typedef float  f32x16  __attribute__((ext_vector_type(16)));
typedef __bf16 bf16_t;
typedef __bf16 bf16x8  __attribute__((ext_vector_type(8)));
typedef unsigned short u16;
typedef unsigned short u16x4 __attribute__((ext_vector_type(4)));
typedef unsigned short u16x8 __attribute__((ext_vector_type(8)));
typedef unsigned int   u32x4 __attribute__((ext_vector_type(4)));

#define DEVI __device__ __forceinline__

static constexpr int CB = 4, CT = 2048, CD = 512, CH = 8, CDH = 64, CINNER = 2048, CK = 31;
static constexpr int CBT = CB * CT;

DEVI u16 f2bf(float f) {
  unsigned u = __builtin_bit_cast(unsigned, f);
  u += 0x7FFFu + ((u >> 16) & 1u);
  return (u16)(u >> 16);
}
DEVI float bf2f(u16 h) { return __builtin_bit_cast(float, (unsigned)h << 16); }
DEVI float sigm(float x) { return 1.0f / (1.0f + __expf(-x)); }

DEVI unsigned cvtpk(float lo, float hi) {
  unsigned r;
  asm("v_cvt_pk_bf16_f32 %0, %1, %2" : "=v"(r) : "v"(lo), "v"(hi));
  return r;
}

DEVI void gload16(const bf16_t* g, bf16_t* l) {
  __builtin_amdgcn_global_load_lds(
      (const __attribute__((address_space(1))) unsigned int*)g,
      (__attribute__((address_space(3))) unsigned int*)l, 16, 0, 0);
}

// exact pipeline tail wait (6 loads/stage): 3 stages in flight -> 12, 2 -> 6, 1 -> 0
DEVI void pipe_wait(int t, int nt) {
  if (t + 3 <= nt)      asm volatile("s_waitcnt vmcnt(12)" ::: "memory");
  else if (t + 2 == nt) asm volatile("s_waitcnt vmcnt(6)" ::: "memory");
  else                  asm volatile("s_waitcnt vmcnt(0)" ::: "memory");
}

enum { EPI_BF = 0, EPI_SILU_BF = 1, EPI_RES = 2, EPI_GLU = 3 };

// ---------------------------------------------------------------------------
// Pipelined wide-N GEMM: 512 thr, BM=256 BN=128 BK=64, 3-stage LDS.
// EPI_GLU: B rows are interleaved [a0-15|b0-15|a16-31|...]; epilogue writes
// a*sigm(b) to half-width output (ldc = N/2), bias = 1024-wide raw pw1 bias.
// ---------------------------------------------------------------------------
template<int EPI>
__global__ __launch_bounds__(512) void gemm8(
    const bf16_t* __restrict__ A, const bf16_t* __restrict__ B,
    const float* __restrict__ bias, const float* __restrict__ res,
    void* __restrict__ Cv,
    int lda, int ldb, int ldc, int Kd, float scale)
{
  __shared__ __align__(16) bf16_t As[3][256 * 64];   // 96 KB
  __shared__ __align__(16) bf16_t Bs[3][128 * 64];   // 48 KB

  const int gx = gridDim.x;
  const int nwg = gx * gridDim.y;
  int wg = blockIdx.y * gx + blockIdx.x;
  wg = (wg & 7) * (nwg >> 3) + (wg >> 3);
  const int m0 = (wg / gx) * 256, n0 = (wg % gx) * 128;

  const int tid = threadIdx.x;
  const int wid = tid >> 6, lane = tid & 63;
  const int lrow = lane & 15, lk = lane >> 4;
  const int wm = (wid >> 1) * 64, wn = (wid & 1) * 64;   // 4x2 wave grid
  const int r = tid >> 3;
  const int cs = (((tid & 7) ^ (r & 7)) << 3);
  const int fsw = lrow & 7;

  auto stage = [&](int kt, int s) {
    const bf16_t* ga = A + (long)(m0 + r) * lda + (kt * 64 + cs);
    const bf16_t* gb = B + (long)(n0 + r) * ldb + (kt * 64 + cs);
    bf16_t* as = &As[s][0];
    bf16_t* bs = &Bs[s][0];
#pragma unroll
    for (int it = 0; it < 4; ++it)
      gload16(ga + (long)it * 64 * lda, as + tid * 8 + it * 4096);
#pragma unroll
    for (int it = 0; it < 2; ++it)
      gload16(gb + (long)it * 64 * ldb, bs + tid * 8 + it * 4096);
  };

  f32x4 acc[4][4] = {};
  const int nt = Kd / 64;

  stage(0, 0);
  stage(1, 1);
  stage(2, 2);

  int s = 0;
  for (int t = 0; t < nt; ++t) {
    pipe_wait(t, nt);
    asm volatile("s_barrier" ::: "memory");

    bf16x8 av[2][4], bv[2][4];
    const bf16_t* as = &As[s][0];
    const bf16_t* bs = &Bs[s][0];
#pragma unroll
    for (int kk = 0; kk < 2; ++kk) {
#pragma unroll
      for (int i = 0; i < 4; ++i)
        av[kk][i] = *(const bf16x8*)&as[(wm + i * 16 + lrow) * 64 + ((((kk << 2) + lk) ^ fsw) << 3)];
#pragma unroll
      for (int j = 0; j < 4; ++j)
        bv[kk][j] = *(const bf16x8*)&bs[(wn + j * 16 + lrow) * 64 + ((((kk << 2) + lk) ^ fsw) << 3)];
    }
    __builtin_amdgcn_s_setprio(1);
#pragma unroll
    for (int kk = 0; kk < 2; ++kk)
#pragma unroll
      for (int i = 0; i < 4; ++i)
#pragma unroll
        for (int j = 0; j < 4; ++j)
          acc[i][j] = __builtin_amdgcn_mfma_f32_16x16x32_bf16(av[kk][i], bv[kk][j], acc[i][j], 0, 0, 0);
    __builtin_amdgcn_s_setprio(0);

    asm volatile("s_barrier" ::: "memory");
    if (t + 3 < nt) stage(t + 3, s);
    s = (s == 2) ? 0 : s + 1;
  }

  if constexpr (EPI == EPI_GLU) {
    // fragments pair: j even = a-frag, j odd = matching b-frag (same lane)
#pragma unroll
    for (int jp = 0; jp < 2; ++jp) {
      int oc = ((n0 + wn) >> 1) + jp * 16 + lrow;
      float ba = bias[oc], bb = bias[512 + oc];
#pragma unroll
      for (int i = 0; i < 4; ++i) {
#pragma unroll
        for (int rr = 0; rr < 4; ++rr) {
          int row = m0 + wm + i * 16 + lk * 4 + rr;
          float av_ = acc[i][2 * jp][rr] + ba;
          float bv_ = acc[i][2 * jp + 1][rr] + bb;
          ((bf16_t*)Cv)[(long)row * ldc + oc] = (bf16_t)(av_ * sigm(bv_));
        }
      }
    }
  } else {
#pragma unroll
    for (int j = 0; j < 4; ++j) {
      int col = n0 + wn + j * 16 + lrow;
      float bb = bias ? bias[col] : 0.0f;
#pragma unroll
      for (int i = 0; i < 4; ++i) {
#pragma unroll
        for (int rr = 0; rr < 4; ++rr) {
          int row = m0 + wm + i * 16 + lk * 4 + rr;
          long idx = (long)row * ldc + col;
          float v = (acc[i][j][rr] + bb) * scale;
          if constexpr (EPI == EPI_SILU_BF) v *= sigm(v);
          if constexpr (EPI == EPI_RES) {
            ((float*)Cv)[idx] = res[idx] + v;
          } else {
            ((bf16_t*)Cv)[idx] = (bf16_t)v;
          }
        }
      }
    }
  }
}

// ---------------------------------------------------------------------------
// Narrow-N bf16 GEMM (2-phase, BK=128 — proven fastest for 64x128 tiles).
// ---------------------------------------------------------------------------
template<int BM, int BN, int BK, int EPI>
__global__ __launch_bounds__(256) void gemm_bf(
    const bf16_t* __restrict__ A, const bf16_t* __restrict__ B,
    const float* __restrict__ bias, const float* __restrict__ res,
    void* __restrict__ Cv,
    int lda, int ldb, int ldc, int Kd, float scale)
{
  __shared__ __align__(16) bf16_t As[BM * BK];
  __shared__ __align__(16) bf16_t Bs[BN * BK];

  const int gx = gridDim.x;
  const int nwg = gx * gridDim.y;
  int wg = blockIdx.y * gx + blockIdx.x;
  wg = (wg & 7) * (nwg >> 3) + (wg >> 3);
  const int m0 = (wg / gx) * BM, n0 = (wg % gx) * BN;

  const int tid = threadIdx.x;
  const int wid = tid >> 6, lane = tid & 63;
  const int lrow = lane & 15, lk = lane >> 4;
  constexpr int FM = BM / 32, FN = BN / 32;
  constexpr int NK = BK / 32;
  constexpr int TPR = BK / 8;
  constexpr int RPP = 256 / TPR;
  const int wm = (wid >> 1) * (BM / 2), wn = (wid & 1) * (BN / 2);
  const int r = tid / TPR;
  const int cs = (((tid & (TPR - 1)) ^ (r & 7)) << 3);
  const int fsw = lrow & 7;

  f32x4 acc[FM][FN] = {};

  for (int k0 = 0; k0 < Kd; k0 += BK) {
    const bf16_t* ga = A + (long)(m0 + r) * lda + (k0 + cs);
    const bf16_t* gb = B + (long)(n0 + r) * ldb + (k0 + cs);
#pragma unroll
    for (int it = 0; it < BM / RPP; ++it)
      gload16(ga + (long)it * RPP * lda, &As[tid * 8 + it * 2048]);
#pragma unroll
    for (int it = 0; it < BN / RPP; ++it)
      gload16(gb + (long)it * RPP * ldb, &Bs[tid * 8 + it * 2048]);
    __syncthreads();

    bf16x8 av[NK][FM], bv[NK][FN];
#pragma unroll
    for (int kk = 0; kk < NK; ++kk) {
#pragma unroll
      for (int i = 0; i < FM; ++i)
        av[kk][i] = *(const bf16x8*)&As[(wm + i * 16 + lrow) * BK + ((((kk << 2) + lk) ^ fsw) << 3)];
#pragma unroll
      for (int j = 0; j < FN; ++j)
        bv[kk][j] = *(const bf16x8*)&Bs[(wn + j * 16 + lrow) * BK + ((((kk << 2) + lk) ^ fsw) << 3)];
    }
#pragma unroll
    for (int kk = 0; kk < NK; ++kk)
#pragma unroll
      for (int i = 0; i < FM; ++i)
#pragma unroll
        for (int j = 0; j < FN; ++j)
          acc[i][j] = __builtin_amdgcn_mfma_f32_16x16x32_bf16(av[kk][i], bv[kk][j], acc[i][j], 0, 0, 0);
    __syncthreads();
  }

#pragma unroll
  for (int j = 0; j < FN; ++j) {
    int col = n0 + wn + j * 16 + lrow;
    float bb = bias ? bias[col] : 0.0f;
#pragma unroll
    for (int i = 0; i < FM; ++i) {
#pragma unroll
      for (int rr = 0; rr < 4; ++rr) {
        int row = m0 + wm + i * 16 + lk * 4 + rr;
        long idx = (long)row * ldc + col;
        float v = (acc[i][j][rr] + bb) * scale;
        if constexpr (EPI == EPI_SILU_BF) v *= sigm(v);
        if constexpr (EPI == EPI_RES) {
          ((float*)Cv)[idx] = res[idx] + v;
        } else {
          ((bf16_t*)Cv)[idx] = (bf16_t)v;
        }
      }
    }
  }
}

// ---------------------------------------------------------------------------
// Flash attention (full KV). Block = 128 q-rows of one (b,h), 4 waves x
// 32 q-rows. K/V LDS double-buffered (static offsets). Softmax in-register:
// tree max + permlane32_swap; row-sum via ones-row MFMA; exp2; defer-max.
// ---------------------------------------------------------------------------
__global__ __launch_bounds__(256) void fattn_k(
    const bf16_t* __restrict__ QK,   // [B*T][1536], Q at 0, K at 512
    const bf16_t* __restrict__ VT,   // [B*H][64][2048]
    bf16_t* __restrict__ O)          // [B*T][512]
{
  __shared__ __align__(16) bf16_t S[16384];      // 32 KB

  const int tid = threadIdx.x;
  const int w = tid >> 6, lane = tid & 63;
  const int l31 = lane & 31, hi = lane >> 5;
  const int q0 = blockIdx.x * 128;
  const int bh = blockIdx.y, b = bh >> 3, h = bh & 7;

  const int r8 = tid >> 3;
  const int csw = ((tid & 7) ^ (r8 & 7)) << 3;
  const int fswl = l31 & 7;

  const bf16_t* Qg = QK + ((long)b * CT + q0) * 1536 + h * 64;
  const bf16_t* Kg = QK + (long)b * CT * 1536 + 512 + h * 64;
  const bf16_t* Vg = VT + (long)bh * 64 * 2048;

#pragma unroll
  for (int it = 0; it < 4; ++it)
    gload16(Qg + (long)(r8 + it * 32) * 1536 + csw, &S[8192 + tid * 8 + it * 2048]);
#pragma unroll
  for (int it = 0; it < 2; ++it)
    gload16(Kg + (long)(r8 + it * 32) * 1536 + csw, &S[tid * 8 + it * 2048]);
#pragma unroll
  for (int it = 0; it < 2; ++it)
    gload16(Vg + (long)(r8 + it * 32) * 2048 + csw, &S[4096 + tid * 8 + it * 2048]);
  __syncthreads();

  bf16x8 qb[4];
#pragma unroll
  for (int m = 0; m < 4; ++m)
    qb[m] = *(const bf16x8*)&S[8192 + (w * 32 + l31) * 64 + (((m * 2 + hi) ^ fswl) << 3)];
  __syncthreads();

  const u16x8 onesu = {0x3F80, 0x3F80, 0x3F80, 0x3F80, 0x3F80, 0x3F80, 0x3F80, 0x3F80};
  const bf16x8 onesf = __builtin_bit_cast(bf16x8, onesu);

  f32x16 o0 = {}, o1 = {}, lacc = {};
  float mrun = -3.0e38f;

#define FA_BODY(CURK, CURV, NXTK, NXTV, KV0, STG)                               \
  {                                                                             \
    if (STG) {                                                                  \
      const int nxt = (KV0) + 64;                                               \
      _Pragma("unroll")                                                         \
      for (int it = 0; it < 2; ++it)                                            \
        gload16(Kg + (long)(nxt + r8 + it * 32) * 1536 + csw,                   \
                &S[(NXTK) + tid * 8 + it * 2048]);                              \
      _Pragma("unroll")                                                         \
      for (int it = 0; it < 2; ++it)                                            \
        gload16(Vg + (long)(r8 + it * 32) * 2048 + nxt + csw,                   \
                &S[(NXTV) + tid * 8 + it * 2048]);                              \
    }                                                                           \
    bf16x8 ka[2][4];                                                            \
    _Pragma("unroll")                                                           \
    for (int j = 0; j < 2; ++j)                                                 \
      _Pragma("unroll")                                                         \
      for (int m = 0; m < 4; ++m)                                               \
        ka[j][m] = *(const bf16x8*)&S[(CURK) + (j * 32 + l31) * 64 +            \
                                      (((m * 2 + hi) ^ fswl) << 3)];            \
    f32x16 s0 = {}, s1 = {};                                                    \
    __builtin_amdgcn_s_setprio(1);                                              \
    _Pragma("unroll")                                                           \
    for (int m = 0; m < 4; ++m) {                                               \
      s0 = __builtin_amdgcn_mfma_f32_32x32x16_bf16(ka[0][m], qb[m], s0, 0, 0, 0); \
      s1 = __builtin_amdgcn_mfma_f32_32x32x16_bf16(ka[1][m], qb[m], s1, 0, 0, 0); \
    }                                                                           \
    __builtin_amdgcn_s_setprio(0);                                              \
    float tm[16];                                                               \
    _Pragma("unroll")                                                           \
    for (int rr = 0; rr < 16; ++rr) tm[rr] = fmaxf(s0[rr], s1[rr]);             \
    _Pragma("unroll")                                                           \
    for (int stp = 8; stp; stp >>= 1)                                           \
      _Pragma("unroll")                                                         \
      for (int rr = 0; rr < stp; ++rr) tm[rr] = fmaxf(tm[rr], tm[rr + stp]);    \
    float pm = tm[0];                                                           \
    { float pa = pm, pb = pm;                                                   \
      asm("v_permlane32_swap_b32 %0, %1" : "+v"(pa), "+v"(pb));                 \
      pm = fmaxf(pa, pb); }                                                     \
    if (!__all(pm <= mrun + 8.0f)) {                                            \
      float mn = fmaxf(mrun, pm);                                               \
      float al = exp2f(mrun - mn);                                              \
      mrun = mn;                                                                \
      lacc[0] *= al;                                                            \
      _Pragma("unroll")                                                         \
      for (int rr = 0; rr < 16; ++rr) { o0[rr] *= al; o1[rr] *= al; }           \
    }                                                                           \
    _Pragma("unroll")                                                           \
    for (int rr = 0; rr < 16; ++rr) s0[rr] = exp2f(s0[rr] - mrun);              \
    _Pragma("unroll")                                                           \
    for (int rr = 0; rr < 16; ++rr) s1[rr] = exp2f(s1[rr] - mrun);              \
    bf16x8 pw[4];                                                               \
    _Pragma("unroll")                                                           \
    for (int jk = 0; jk < 4; ++jk) {                                            \
      float e0, e1, e2, e3, e4, e5, e6, e7;                                     \
      if (jk == 0) { e0=s0[0];e1=s0[1];e2=s0[2];e3=s0[3];e4=s0[4];e5=s0[5];e6=s0[6];e7=s0[7]; }        \
      else if (jk == 1) { e0=s0[8];e1=s0[9];e2=s0[10];e3=s0[11];e4=s0[12];e5=s0[13];e6=s0[14];e7=s0[15]; } \
      else if (jk == 2) { e0=s1[0];e1=s1[1];e2=s1[2];e3=s1[3];e4=s1[4];e5=s1[5];e6=s1[6];e7=s1[7]; }   \
      else { e0=s1[8];e1=s1[9];e2=s1[10];e3=s1[11];e4=s1[12];e5=s1[13];e6=s1[14];e7=s1[15]; }          \
      unsigned a0 = cvtpk(e0, e1), a1 = cvtpk(e2, e3);                          \
      unsigned b0 = cvtpk(e4, e5), b1 = cvtpk(e6, e7);                          \
      asm("v_permlane32_swap_b32 %0, %1" : "+v"(a0), "+v"(b0));                 \
      asm("v_permlane32_swap_b32 %0, %1" : "+v"(a1), "+v"(b1));                 \
      u32x4 t; t[0] = a0; t[1] = a1; t[2] = b0; t[3] = b1;                      \
      pw[jk] = __builtin_bit_cast(bf16x8, t);                                   \
    }                                                                           \
    bf16x8 va[2][4];                                                            \
    _Pragma("unroll")                                                           \
    for (int n = 0; n < 2; ++n)                                                 \
      _Pragma("unroll")                                                         \
      for (int jk = 0; jk < 4; ++jk)                                            \
        va[n][jk] = *(const bf16x8*)&S[(CURV) + (n * 32 + l31) * 64 +           \
                                       (((jk * 2 + hi) ^ fswl) << 3)];          \
    __builtin_amdgcn_s_setprio(1);                                              \
    _Pragma("unroll")                                                           \
    for (int jk = 0; jk < 4; ++jk) {                                            \
      o0 = __builtin_amdgcn_mfma_f32_32x32x16_bf16(va[0][jk], pw[jk], o0, 0, 0, 0); \
      o1 = __builtin_amdgcn_mfma_f32_32x32x16_bf16(va[1][jk], pw[jk], o1, 0, 0, 0); \
      lacc = __builtin_amdgcn_mfma_f32_32x32x16_bf16(onesf, pw[jk], lacc, 0, 0, 0); \
    }                                                                           \
    __builtin_amdgcn_s_setprio(0);                                              \
    __syncthreads();                                                            \
  }

  for (int kv0 = 0; kv0 < CT; kv0 += 128) {
    FA_BODY(0, 4096, 8192, 12288, kv0, 1)
    FA_BODY(8192, 12288, 0, 4096, kv0 + 64, (kv0 + 128 < CT))
  }
#undef FA_BODY

  float rl = 1.0f / lacc[0];
  bf16_t* Op = O + ((long)b * CT + q0 + w * 32 + l31) * CD + h * 64;
#pragma unroll
  for (int n = 0; n < 2; ++n) {
#pragma unroll
    for (int m = 0; m < 4; ++m) {
      u16x4 pk4;
#pragma unroll
      for (int e = 0; e < 4; ++e)
        pk4[e] = f2bf((n ? o1[m * 4 + e] : o0[m * 4 + e]) * rl);
      *(u16x4*)(Op + n * 32 + m * 8 + hi * 4) = pk4;
    }
  }
}

// ---------------------------------------------------------------------------
// Weight convert+transpose: w[K][N] f32 -> o[N][K] bf16. 64x64 tiles.
// ---------------------------------------------------------------------------
__global__ __launch_bounds__(256) void wtrans_k(
    const float* __restrict__ w, u16* __restrict__ o, int Kd, int N)
{
  __shared__ u16 lt[64][72];
  const int k0 = blockIdx.y * 64, n0 = blockIdx.x * 64;
  const int tid = threadIdx.x;
#pragma unroll
  for (int it = 0; it < 4; ++it) {
    int kk = (tid >> 4) + it * 16, nn = (tid & 15) * 4;
    float4 f = *(const float4*)(w + (long)(k0 + kk) * N + n0 + nn);
    lt[kk][nn + 0] = f2bf(f.x); lt[kk][nn + 1] = f2bf(f.y);
    lt[kk][nn + 2] = f2bf(f.z); lt[kk][nn + 3] = f2bf(f.w);
  }
  __syncthreads();
#pragma unroll
  for (int it = 0; it < 2; ++it) {
    int nn = (tid >> 3) + it * 32, kk = (tid & 7) * 8;
    u16x8 pk;
#pragma unroll
    for (int e = 0; e < 8; ++e) pk[e] = lt[kk + e][nn];
    *(u16x8*)(o + (long)(n0 + nn) * Kd + k0 + kk) = pk;
  }
}

// pw1 weight transpose with GLU row interleave: w[512][1024] f32 ->
// o[1024][512] bf16, dest row d for source col s: d = ((s&511)>>4)*32 +
// (s>>9)*16 + (s&15)  (a/b 16-col groups interleaved).
__global__ __launch_bounds__(256) void pwtrans_k(
    const float* __restrict__ w, u16* __restrict__ o)
{
  __shared__ u16 lt[64][72];
  const int k0 = blockIdx.y * 64, n0 = blockIdx.x * 64;
  const int tid = threadIdx.x;
#pragma unroll
  for (int it = 0; it < 4; ++it) {
    int kk = (tid >> 4) + it * 16, nn = (tid & 15) * 4;
    float4 f = *(const float4*)(w + (long)(k0 + kk) * 1024 + n0 + nn);
    lt[kk][nn + 0] = f2bf(f.x); lt[kk][nn + 1] = f2bf(f.y);
    lt[kk][nn + 2] = f2bf(f.z); lt[kk][nn + 3] = f2bf(f.w);
  }
  __syncthreads();
#pragma unroll
  for (int it = 0; it < 2; ++it) {
    int nn = (tid >> 3) + it * 32, kk = (tid & 7) * 8;
    int s = n0 + nn;
    int d = ((s & 511) >> 4) * 32 + (s >> 9) * 16 + (s & 15);
    u16x8 pk;
#pragma unroll
    for (int e = 0; e < 8; ++e) pk[e] = lt[kk + e][nn];
    *(u16x8*)(o + (long)d * 512 + k0 + kk) = pk;
  }
}

// V columns of bufQKV -> VT[bh][d][t]
__global__ __launch_bounds__(256) void vtrans_k(
    const u16* __restrict__ v, u16* __restrict__ vt)
{
  __shared__ u16 lt[64][72];
  const int bh = blockIdx.y, b = bh >> 3, h = bh & 7;
  const int t0 = blockIdx.x * 64;
  const int tid = threadIdx.x;
#pragma unroll
  for (int it = 0; it < 2; ++it) {
    int tt = (tid >> 3) + it * 32, dd = (tid & 7) * 8;
    u16x8 vv = *(const u16x8*)(v + ((long)b * CT + t0 + tt) * 1536 + 1024 + h * 64 + dd);
#pragma unroll
    for (int e = 0; e < 8; ++e) lt[tt][dd + e] = vv[e];
  }
  __syncthreads();
#pragma unroll
  for (int it = 0; it < 2; ++it) {
    int dd = (tid >> 3) + it * 32, tt = (tid & 7) * 8;
    u16x8 pk;
#pragma unroll
    for (int e = 0; e < 8; ++e) pk[e] = lt[tt + e][dd];
    *(u16x8*)(vt + ((long)bh * 64 + dd) * CT + t0 + tt) = pk;
  }
}

// dw_w[512][31] f32 -> wT[31][512] f32
__global__ void dwt_k(const float* __restrict__ w, float* __restrict__ o)
{
  int i = blockIdx.x * 256 + threadIdx.x;
  if (i < 512 * 31) { int c = i / 31, k = i % 31; o[k * 512 + c] = w[i]; }
}

// ---------------------------------------------------------------------------
// LayerNorm over D=512, one block per row.
// ---------------------------------------------------------------------------
template<int OBF>
__global__ __launch_bounds__(256) void ln_k(
    const float* __restrict__ in, const float* __restrict__ g,
    const float* __restrict__ b, void* __restrict__ out)
{
  __shared__ float rs[4], rq[4];
  const long row = blockIdx.x;
  const int tid = threadIdx.x;
  float2 v = ((const float2*)(in + row * CD))[tid];
  float s = v.x + v.y, q = v.x * v.x + v.y * v.y;
#pragma unroll
  for (int o = 32; o; o >>= 1) { s += __shfl_xor(s, o); q += __shfl_xor(q, o); }
  if ((tid & 63) == 0) { rs[tid >> 6] = s; rq[tid >> 6] = q; }
  __syncthreads();
  s = rs[0] + rs[1] + rs[2] + rs[3];
  q = rq[0] + rq[1] + rq[2] + rq[3];
  float mean = s * (1.0f / CD);
  float var = q * (1.0f / CD) - mean * mean;
  float rstd = rsqrtf(var + 1e-5f);
  float2 gg = ((const float2*)g)[tid];
  float2 bb = ((const float2*)b)[tid];
  float ox = (v.x - mean) * rstd * gg.x + bb.x;
  float oy = (v.y - mean) * rstd * gg.y + bb.y;
  if (OBF) {
    unsigned pk = ((unsigned)f2bf(oy) << 16) | f2bf(ox);
    ((unsigned*)out)[row * 256 + tid] = pk;
  } else {
    ((float2*)out)[row * 256 + tid] = make_float2(ox, oy);
  }
}

__global__ void rope_table_k(float* __restrict__ cosT, float* __restrict__ sinT)
{
  int tid = blockIdx.x * 256 + threadIdx.x;     // T*32
  int t = tid >> 5, i = tid & 31;
  float freq = __expf(-(float)i * (9.210340371976184f / 32.0f));
  float ang = (float)t * freq;
  cosT[tid] = cosf(ang);
  sinT[tid] = sinf(ang);
}

// In-place RoPE on fused QKV (Q cols 0..511 scaled by 0.125*log2e, K 512..1023).
__global__ __launch_bounds__(256) void rope_k(
    unsigned* __restrict__ qkv,
    const float* __restrict__ cosT, const float* __restrict__ sinT)
{
  const float SC = 0.125f * 1.44269504089f;
  long p = (long)blockIdx.x * 256 + threadIdx.x;
  int pr = (int)(p & 255);
  long row = p >> 8;
  int t = (int)(row & (CT - 1));
  int h = pr >> 5, i = pr & 31;
  float c = cosT[t * 32 + i], s = sinT[t * 32 + i];
  unsigned* base = qkv + row * 768 + h * 32 + i;
  unsigned v = base[0];
  float xe = bf2f((u16)v), xo = bf2f((u16)(v >> 16));
  base[0] = ((unsigned)f2bf((xe * s + xo * c) * SC) << 16) | f2bf((xe * c - xo * s) * SC);
  v = base[256];
  xe = bf2f((u16)v); xo = bf2f((u16)(v >> 16));
  base[256] = ((unsigned)f2bf(xe * s + xo * c) << 16) | f2bf(xe * c - xo * s);
}

// Depthwise conv1d: bf16 in, bf16 out. 8 t-outputs x 4 channels/thread.
__global__ __launch_bounds__(256) void dwconv_k(
    const u16* __restrict__ in, const float* __restrict__ wT,
    const float* __restrict__ wb, u16* __restrict__ out)
{
  long idx = (long)blockIdx.x * 256 + threadIdx.x;
  int c4 = (int)(idx & 127) * 4;
  int t0 = (int)((idx >> 7) & 255) * 8;
  int b = (int)(idx >> 15);
  const u16* base = in + (long)b * CT * CD;
  float4 bias = *(const float4*)(wb + c4);
  float4 acc[8];
#pragma unroll
  for (int t = 0; t < 8; ++t) acc[t] = bias;
#pragma unroll
  for (int j = 0; j < 38; ++j) {
    int tr = t0 + j - 15;
    float4 row = make_float4(0.f, 0.f, 0.f, 0.f);
    if (tr >= 0 && tr < CT) {
      u16x4 rv = *(const u16x4*)(base + (long)tr * CD + c4);
      row = make_float4(bf2f(rv[0]), bf2f(rv[1]), bf2f(rv[2]), bf2f(rv[3]));
    }
#pragma unroll
    for (int t = 0; t < 8; ++t) {
      int k = j - t;
      if (k >= 0 && k < CK) {
        float4 w4 = *(const float4*)(wT + k * CD + c4);
        acc[t].x += row.x * w4.x; acc[t].y += row.y * w4.y;
        acc[t].z += row.z * w4.z; acc[t].w += row.w * w4.w;
      }
    }
  }
#pragma unroll
  for (int t = 0; t < 8; ++t) {
    u16x4 pk;
    pk[0] = f2bf(acc[t].x); pk[1] = f2bf(acc[t].y);
    pk[2] = f2bf(acc[t].z); pk[3] = f2bf(acc[t].w);
    *(u16x4*)(out + ((long)b * CT + t0 + t) * CD + c4) = pk;
  }
}

__global__ __launch_bounds__(256) void bn_part_k(
    const u16* __restrict__ in, float* __restrict__ psum, float* __restrict__ psq)
{
  const int blk = blockIdx.x;        // 256
  const int tid = threadIdx.x;
  const int c0 = tid, c1 = tid + 256;
  const int rows = CBT / 256;
  const u16* base = in + (long)blk * rows * CD;
  float s0 = 0, q0 = 0, s1 = 0, q1 = 0;
  for (int r = 0; r < rows; ++r) {
    float v0 = bf2f(base[(long)r * CD + c0]); s0 += v0; q0 += v0 * v0;
    float v1 = bf2f(base[(long)r * CD + c1]); s1 += v1; q1 += v1 * v1;
  }
  psum[blk * CD + c0] = s0; psq[blk * CD + c0] = q0;
  psum[blk * CD + c1] = s1; psq[blk * CD + c1] = q1;
}

__global__ __launch_bounds__(256) void bn_fin_k(
    const float* __restrict__ psum, const float* __restrict__ psq,
    float* __restrict__ stat)
{
  int c = blockIdx.x * 256 + threadIdx.x;
  float s = 0, q = 0;
  for (int i = 0; i < 256; ++i) { s += psum[i * CD + c]; q += psq[i * CD + c]; }
  float mean = s * (1.0f / CBT);
  float var = q * (1.0f / CBT) - mean * mean;
  stat[c] = mean;
  stat[CD + c] = rsqrtf(var + 1e-5f);
}

__global__ __launch_bounds__(256) void bn_app_k(
    const u16* __restrict__ h, const float* __restrict__ stat,
    const float* __restrict__ g, const float* __restrict__ b,
    u16* __restrict__ out)
{
  long idx = (long)blockIdx.x * 256 + threadIdx.x;
  int c = (int)(idx & 511);
  float v = (bf2f(h[idx]) - stat[c]) * stat[CD + c] * g[c] + b[c];
  v = v * sigm(v);
  out[idx] = f2bf(v);
}

// ---------------------------------------------------------------------------
// Host launcher
// ---------------------------------------------------------------------------
extern "C" void kernel_launch(void* const* d_in, const int* in_sizes, int n_in,
                              void* d_out, int out_size, void* d_ws, size_t ws_size,
                              hipStream_t stream)
{
  const float* x        = (const float*)d_in[0];
  const float* ff1_lng  = (const float*)d_in[1];
  const float* ff1_lnb  = (const float*)d_in[2];
  const float* ff1_w1   = (const float*)d_in[3];
  const float* ff1_b1   = (const float*)d_in[4];
  const float* ff1_w2   = (const float*)d_in[5];
  const float* ff1_b2   = (const float*)d_in[6];
  const float* attn_lng = (const float*)d_in[7];
  const float* attn_lnb = (const float*)d_in[8];
  const float* wq       = (const float*)d_in[9];
  const float* wk       = (const float*)d_in[10];
  const float* wv       = (const float*)d_in[11];
  const float* wo       = (const float*)d_in[12];
  const float* conv_lng = (const float*)d_in[13];
  const float* conv_lnb = (const float*)d_in[14];
  const float* pw1_w    = (const float*)d_in[15];
  const float* pw1_b    = (const float*)d_in[16];
  const float* dw_w     = (const float*)d_in[17];
  const float* dw_b     = (const float*)d_in[18];
  const float* bn_g     = (const float*)d_in[19];
  const float* bn_b     = (const float*)d_in[20];
  const float* pw2_w    = (const float*)d_in[21];
  const float* pw2_b    = (const float*)d_in[22];
  const float* ff2_lng  = (const float*)d_in[23];
  const float* ff2_lnb  = (const float*)d_in[24];
  const float* ff2_w1   = (const float*)d_in[25];
  const float* ff2_b1   = (const float*)d_in[26];
  const float* ff2_w2   = (const float*)d_in[27];
  const float* ff2_b2   = (const float*)d_in[28];
  const float* out_lng  = (const float*)d_in[29];
  const float* out_lnb  = (const float*)d_in[30];
  float* out = (float*)d_out;

  char* p = (char*)d_ws;
  auto alloc = [&](size_t bytes) { char* r = p; p += (bytes + 255) & ~(size_t)255; return r; };
  float*  bufX   = (float*)alloc((size_t)CBT * CD * 4);
  bf16_t* bufH   = (bf16_t*)alloc((size_t)CBT * CD * 2);
  bf16_t* bufQKV = (bf16_t*)alloc((size_t)CBT * 1536 * 2);
  bf16_t* bufO   = (bf16_t*)alloc((size_t)CBT * CD * 2);
  bf16_t* bufVT  = (bf16_t*)alloc((size_t)CBT * CD * 2);
  bf16_t* bufP   = (bf16_t*)alloc((size_t)CBT * CINNER * 2);
  bf16_t* w_ff1a = (bf16_t*)alloc((size_t)CD * CINNER * 2);
  bf16_t* w_ff1b = (bf16_t*)alloc((size_t)CD * CINNER * 2);
  bf16_t* w_qkv  = (bf16_t*)alloc((size_t)CD * 1536 * 2);
  bf16_t* w_o    = (bf16_t*)alloc((size_t)CD * CD * 2);
  bf16_t* w_pw1  = (bf16_t*)alloc((size_t)CD * 2 * CD * 2);
  bf16_t* w_pw2  = (bf16_t*)alloc((size_t)CD * CD * 2);
  bf16_t* w_ff2a = (bf16_t*)alloc((size_t)CD * CINNER * 2);
  bf16_t* w_ff2b = (bf16_t*)alloc((size_t)CD * CINNER * 2);
  float* dwT  = (float*)alloc((size_t)CK * CD * 4);
  float* cosT = (float*)alloc((size_t)CT * 32 * 4);
  float* sinT = (float*)alloc((size_t)CT * 32 * 4);
  float* psum = (float*)alloc((size_t)256 * CD * 4);
  float* psq  = (float*)alloc((size_t)256 * CD * 4);
  float* stat = (float*)alloc((size_t)2 * CD * 4);

  const dim3 blk(256);
  const dim3 blk8(512);

  wtrans_k<<<dim3(CINNER / 64, CD / 64), blk, 0, stream>>>(ff1_w1, (u16*)w_ff1a, CD, CINNER);
  wtrans_k<<<dim3(CD / 64, CINNER / 64), blk, 0, stream>>>(ff1_w2, (u16*)w_ff1b, CINNER, CD);
  wtrans_k<<<dim3(CD / 64, CD / 64), blk, 0, stream>>>(wq, (u16*)w_qkv, CD, CD);
  wtrans_k<<<dim3(CD / 64, CD / 64), blk, 0, stream>>>(wk, (u16*)(w_qkv + (size_t)512 * CD), CD, CD);
  wtrans_k<<<dim3(CD / 64, CD / 64), blk, 0, stream>>>(wv, (u16*)(w_qkv + (size_t)1024 * CD), CD, CD);
  wtrans_k<<<dim3(CD / 64, CD / 64), blk, 0, stream>>>(wo, (u16*)w_o, CD, CD);
  pwtrans_k<<<dim3(1024 / 64, CD / 64), blk, 0, stream>>>(pw1_w, (u16*)w_pw1);
  wtrans_k<<<dim3(CD / 64, CD / 64), blk, 0, stream>>>(pw2_w, (u16*)w_pw2, CD, CD);
  wtrans_k<<<dim3(CINNER / 64, CD / 64), blk, 0, stream>>>(ff2_w1, (u16*)w_ff2a, CD, CINNER);
  wtrans_k<<<dim3(CD / 64, CINNER / 64), blk, 0, stream>>>(ff2_w2, (u16*)w_ff2b, CINNER, CD);
  dwt_k<<<dim3(62), blk, 0, stream>>>(dw_w, dwT);
  rope_table_k<<<dim3(CT * 32 / 256), blk, 0, stream>>>(cosT, sinT);

  // ---- FF1 ----
  ln_k<1><<<dim3(CBT), blk, 0, stream>>>(x, ff1_lng, ff1_lnb, bufH);
  gemm8<EPI_SILU_BF><<<dim3(16, 32), blk8, 0, stream>>>(
      bufH, w_ff1a, ff1_b1, nullptr, bufP, CD, CD, CINNER, CD, 1.0f);
  gemm_bf<64, 128, 128, EPI_RES><<<dim3(4, 128), blk, 0, stream>>>(
      bufP, w_ff1b, ff1_b2, x, bufX, CINNER, CINNER, CD, CINNER, 0.5f);

  // ---- Attention ----
  ln_k<1><<<dim3(CBT), blk, 0, stream>>>(bufX, attn_lng, attn_lnb, bufH);
  gemm8<EPI_BF><<<dim3(12, 32), blk8, 0, stream>>>(
      bufH, w_qkv, nullptr, nullptr, bufQKV, CD, CD, 1536, CD, 1.0f);
  rope_k<<<dim3(CB * CT), blk, 0, stream>>>((unsigned*)bufQKV, cosT, sinT);
  vtrans_k<<<dim3(CT / 64, CB * CH), blk, 0, stream>>>((const u16*)bufQKV, (u16*)bufVT);
  fattn_k<<<dim3(CT / 128, CB * CH), blk, 0, stream>>>(bufQKV, bufVT, bufO);
  gemm_bf<64, 128, 128, EPI_RES><<<dim3(4, 128), blk, 0, stream>>>(
      bufO, w_o, nullptr, bufX, bufX, CD, CD, CD, CD, 1.0f);

  // ---- Conv module ----
  ln_k<1><<<dim3(CBT), blk, 0, stream>>>(bufX, conv_lng, conv_lnb, bufH);
  gemm8<EPI_GLU><<<dim3(8, 32), blk8, 0, stream>>>(
      bufH, w_pw1, pw1_b, nullptr, bufH, CD, CD, CD, CD, 1.0f);
  dwconv_k<<<dim3(512), blk, 0, stream>>>((const u16*)bufH, dwT, dw_b, (u16*)bufO);
  bn_part_k<<<dim3(256), blk, 0, stream>>>((const u16*)bufO, psum, psq);
  bn_fin_k<<<dim3(2), blk, 0, stream>>>(psum, psq, stat);
  bn_app_k<<<dim3(CBT * CD / 256), blk, 0, stream>>>((const u16*)bufO, stat, bn_g, bn_b, (u16*)bufH);
  gemm_bf<64, 128, 128, EPI_RES><<<dim3(4, 128), blk, 0, stream>>>(
      bufH, w_pw2, pw2_b, bufX, bufX, CD, CD, CD, CD, 1.0f);

  // ---- FF2 ----
  ln_k<1><<<dim3(CBT), blk, 0, stream>>>(bufX, ff2_lng, ff2_lnb, bufH);
  gemm8<EPI_SILU_BF><<<dim3(16, 32), blk8, 0, stream>>>(
      bufH, w_ff2a, ff2_b1, nullptr, bufP, CD, CD, CINNER, CD, 1.0f);
  gemm_bf<64, 128, 128, EPI_RES><<<dim3(4, 128), blk, 0, stream>>>(
      bufP, w_ff2b, ff2_b2, bufX, bufX, CINNER, CINNER, CD, CINNER, 0.5f);

  // ---- Output LN ----
  ln_k<0><<<dim3(CBT), blk, 0, stream>>>(bufX, out_lng, out_lnb, out);

  (void)in_sizes; (void)n_in; (void)out_size; (void)ws_size;
}